// Round 17
// baseline (1251.900 us; speedup 1.0000x reference)
//
#include <hip/hip_runtime.h>
#include <hip/hip_bf16.h>
#include <math.h>

// Problem dims (fixed)
#define BDIM 4
#define TDIM 1024
#define DDIM 1024
#define DH   128
#define NELEM ((size_t)BDIM * TDIM * DDIM)   // 4,194,304

typedef __attribute__((ext_vector_type(8))) _Float16 hfrag;  // 8 f16 (4 VGPR)
typedef __attribute__((ext_vector_type(4))) float facc;      // 4 f32 acc

// f16 2-plane split: x = h1 + h2/2048 (22 mantissa bits). Proven R13-R15.
__device__ __forceinline__ void split2(float x, ushort& h1, ushort& h2) {
  const _Float16 a = (_Float16)x;
  const _Float16 b = (_Float16)((x - (float)a) * 2048.0f);
  union { _Float16 h; ushort u; } ua, ub;
  ua.h = a; ub.h = b;
  h1 = ua.u; h2 = ub.u;
}
#define INV2048 4.8828125e-4f    // 1/2048, exact

// Fast exp: v_exp_f32(x*log2e). Proven R14/R15.
__device__ __forceinline__ float fexp(float x) {
  return __builtin_amdgcn_exp2f(x * 1.4426950408889634f);
}

constexpr int GM = 4096, GN = 1024, GK = 1024;
constexpr int BM = 128, BK = 32;
constexpr int BKP = 40;                     // padded LDS k-dim (80 B rows)
constexpr size_t PSA = (size_t)GM * 1024;   // A-plane stride (ushorts)

// ---------------------------------------------------------------------------
// cvt_h2t: up to 3 weight matrices [1024][1024] f32 -> 2-plane f16 split,
// blocked-transposed [kTot/32][N=1024][32].
// ---------------------------------------------------------------------------
__global__ __launch_bounds__(256)
void cvt_h2t(const float* __restrict__ W0, const float* __restrict__ W1,
             const float* __restrict__ W2, ushort* __restrict__ P,
             int zstride, int zkoff, int kTot) {
  __shared__ float Ls[64][68];
  const int z = blockIdx.z;
  const float* W = (z == 0) ? W0 : (z == 1 ? W1 : W2);
  ushort* Pz = P + (size_t)z * zstride;
  const size_t PS = (size_t)kTot * GN;     // ushorts per plane
  const int t = threadIdx.x;
  const int k0 = blockIdx.x * 64, n0 = blockIdx.y * 64;
  const int r = t >> 4, c4 = (t & 15) << 2;
#pragma unroll
  for (int i = 0; i < 4; ++i)
    *(float4*)&Ls[r + i * 16][c4] =
        *(const float4*)(W + (size_t)(k0 + r + i * 16) * GN + n0 + c4);
  __syncthreads();
  const int n = t >> 2, kc = (t & 3) << 4;
  uint p1[8], p2[8];
#pragma unroll
  for (int jj = 0; jj < 8; ++jj) {
    const float x0 = Ls[kc + 2 * jj][n], x1 = Ls[kc + 2 * jj + 1][n];
    ushort a1, a2, b1, b2;
    split2(x0, a1, a2);
    split2(x1, b1, b2);
    p1[jj] = (uint)a1 | ((uint)b1 << 16);
    p2[jj] = (uint)a2 | ((uint)b2 << 16);
  }
  const int kk = k0 + kc + z * zkoff;
  ushort* d = Pz + (size_t)(kk >> 5) * (GN * 32) + (size_t)(n0 + n) * 32 + (kk & 31);
  *(uint4*)(d)          = *(uint4*)&p1[0];
  *(uint4*)(d + 8)      = *(uint4*)&p1[4];
  *(uint4*)(d + PS)     = *(uint4*)&p2[0];
  *(uint4*)(d + PS + 8) = *(uint4*)&p2[4];
}

// ---------------------------------------------------------------------------
// GEMM body with COMPILE-TIME A-mode (R16 post-mortem: runtime mode kept all
// three A-register sets live -> scratch spill, 1 GB/dispatch writes).
// MODE: 0 = f32 (split in-kernel), 1 = u8 spikes (exact, 2 passes),
// 2 = pre-split planes [2][4096][1024] ushort (pure-copy staging).
// ---------------------------------------------------------------------------
template<int EPI, int MODE, int KTOT>
__device__ __forceinline__ void gemm_body(
    const void* __restrict__ Abase, const void* __restrict__ Ak2,
    const ushort* __restrict__ pBm, float* __restrict__ C,
    ushort (&As)[2][BM][BKP], ushort (&Bs)[2][64][BKP],
    const int row0, const int col0, const int tid) {
  constexpr size_t PS = (size_t)KTOT * GN;   // B-plane stride (ushorts)
  const int sm  = tid & 127;
  const int sk0 = (tid >> 7) << 4;

  const int wave = tid >> 6;
  const int lane = tid & 63;
  const int wrow = (wave >> 1) * 64;
  const int wcol = (wave & 1) * 32;
  const int lrow = lane & 15;
  const int kof  = (lane >> 4) * 8;

  facc accM[4][2], accS[4][2];
#pragma unroll
  for (int i = 0; i < 4; ++i)
#pragma unroll
    for (int j = 0; j < 2; ++j) { accM[i][j] = (facc)0.f; accS[i][j] = (facc)0.f; }

  float av[16];      // MODE 0 only (if constexpr -> DCE otherwise)
  uint4 a8raw;       // MODE 1 only
  uint4 apre[4];     // MODE 2 only
  uint4 bregs[2];

  auto gloadA = [&](int K0) {
    const void* src = Abase; int k = K0;
    if (KTOT > 1024 && K0 >= 1024) { src = Ak2; k = K0 - 1024; }
    if constexpr (MODE == 1) {
      a8raw = *(const uint4*)((const uint8_t*)src + (size_t)(row0 + sm) * 1024 + k + sk0);
    } else if constexpr (MODE == 2) {
      const ushort* Ap = (const ushort*)src + (size_t)(row0 + sm) * 1024 + k + sk0;
      apre[0] = *(const uint4*)(Ap);
      apre[1] = *(const uint4*)(Ap + 8);
      apre[2] = *(const uint4*)(Ap + PSA);
      apre[3] = *(const uint4*)(Ap + PSA + 8);
    } else {
      const float* Ap = (const float*)src + (size_t)(row0 + sm) * 1024 + k + sk0;
      *(float4*)&av[0]  = *(const float4*)(Ap);
      *(float4*)&av[4]  = *(const float4*)(Ap + 4);
      *(float4*)&av[8]  = *(const float4*)(Ap + 8);
      *(float4*)&av[12] = *(const float4*)(Ap + 12);
    }
  };
  auto gloadB = [&](int K0) {
    const int kb = K0 >> 5;
#pragma unroll
    for (int j = 0; j < 2; ++j) {
      const int u = tid + 256 * j;
      const int q = u & 3, nn = (u >> 2) & 63, p = u >> 8;
      bregs[j] = *(const uint4*)(pBm + (size_t)p * PS + (size_t)kb * (GN * 32)
                                 + (size_t)(col0 + nn) * 32 + q * 8);
    }
  };
  auto swrite = [&]() {
    if constexpr (MODE == 1) {
      const uint w4[4] = {a8raw.x, a8raw.y, a8raw.z, a8raw.w};
      uint pk[8];
#pragma unroll
      for (int i = 0; i < 8; ++i) {
        const uint b0 = (w4[i >> 1] >> ((i & 1) * 16)) & 0xFFu;
        const uint b1 = (w4[i >> 1] >> ((i & 1) * 16 + 8)) & 0xFFu;
        pk[i] = (b0 * 0x3C00u) | ((b1 * 0x3C00u) << 16);   // f16 1.0 = 0x3C00
      }
      *(uint4*)&As[0][sm][sk0]     = *(uint4*)&pk[0];
      *(uint4*)&As[0][sm][sk0 + 8] = *(uint4*)&pk[4];
    } else if constexpr (MODE == 2) {
      *(uint4*)&As[0][sm][sk0]     = apre[0];
      *(uint4*)&As[0][sm][sk0 + 8] = apre[1];
      *(uint4*)&As[1][sm][sk0]     = apre[2];
      *(uint4*)&As[1][sm][sk0 + 8] = apre[3];
    } else {
      uint q1[8], q2[8];
#pragma unroll
      for (int i = 0; i < 8; ++i) {
        ushort a1, a2, b1, b2;
        split2(av[2 * i], a1, a2);
        split2(av[2 * i + 1], b1, b2);
        q1[i] = (uint)a1 | ((uint)b1 << 16);
        q2[i] = (uint)a2 | ((uint)b2 << 16);
      }
      *(uint4*)&As[0][sm][sk0]     = *(uint4*)&q1[0];
      *(uint4*)&As[0][sm][sk0 + 8] = *(uint4*)&q1[4];
      *(uint4*)&As[1][sm][sk0]     = *(uint4*)&q2[0];
      *(uint4*)&As[1][sm][sk0 + 8] = *(uint4*)&q2[4];
    }
#pragma unroll
    for (int j = 0; j < 2; ++j) {
      const int u = tid + 256 * j;
      const int q = u & 3, nn = (u >> 2) & 63, p = u >> 8;
      *(uint4*)&Bs[p][nn][q * 8] = bregs[j];
    }
  };

  gloadA(0); gloadB(0);
  for (int k0 = 0; k0 < KTOT; k0 += BK) {
    __syncthreads();
    swrite();
    const int kn = k0 + BK;
    if (kn < KTOT) { gloadA(kn); gloadB(kn); }
    __syncthreads();
    hfrag fb1[2], fb2[2];
#pragma unroll
    for (int f = 0; f < 2; ++f) {
      fb1[f] = *(const hfrag*)&Bs[0][wcol + f * 16 + lrow][kof];
      fb2[f] = *(const hfrag*)&Bs[1][wcol + f * 16 + lrow][kof];
    }
#pragma unroll
    for (int mi = 0; mi < 4; ++mi) {
      const hfrag a1 = *(const hfrag*)&As[0][wrow + mi * 16 + lrow][kof];
      hfrag a2;
      if constexpr (MODE != 1) a2 = *(const hfrag*)&As[1][wrow + mi * 16 + lrow][kof];
#pragma unroll
      for (int ni = 0; ni < 2; ++ni)
        accM[mi][ni] = __builtin_amdgcn_mfma_f32_16x16x32_f16(a1, fb1[ni], accM[mi][ni], 0, 0, 0);
#pragma unroll
      for (int ni = 0; ni < 2; ++ni) {
        accS[mi][ni] = __builtin_amdgcn_mfma_f32_16x16x32_f16(a1, fb2[ni], accS[mi][ni], 0, 0, 0);
        if constexpr (MODE != 1)
          accS[mi][ni] = __builtin_amdgcn_mfma_f32_16x16x32_f16(a2, fb1[ni], accS[mi][ni], 0, 0, 0);
      }
    }
  }

  // epilogue: D frag col = lane&15, row = (lane>>4)*4 + reg (m89/m91).
#pragma unroll
  for (int mi = 0; mi < 4; ++mi) {
#pragma unroll
    for (int ni = 0; ni < 2; ++ni) {
      const int rbase = row0 + wrow + mi * 16 + (lane >> 4) * 4;
      const int cc    = col0 + wcol + ni * 16 + lrow;
      float* cp = C + (size_t)rbase * GN + cc;
#pragma unroll
      for (int r = 0; r < 4; ++r) {
        float v = accM[mi][ni][r] + accS[mi][ni][r] * INV2048;
        if (EPI == 1) v += cp[(size_t)r * GN];
        cp[(size_t)r * GN] = v;
      }
    }
  }
}

template<int EPI, int M0, int M1, int M2, int KTOT>
__global__ __launch_bounds__(256)
void gemm_k(const void* __restrict__ A0, const void* __restrict__ A1,
            const void* __restrict__ A2, const void* __restrict__ Ak2,
            const ushort* __restrict__ pB,
            float* __restrict__ C0, float* __restrict__ C1,
            float* __restrict__ C2) {
  __shared__ ushort As[2][BM][BKP];
  __shared__ ushort Bs[2][64][BKP];
  constexpr size_t PS = (size_t)KTOT * GN;
  const int tid = threadIdx.x;
  const int n   = blockIdx.x;
  const int xcd = n & 7;
  const int idx = n >> 3;
  const int by  = xcd * 4 + (idx & 3);
  const int bx  = idx >> 2;
  const int mat = bx >> 4;
  const int row0 = by * BM;
  const int col0 = (bx & 15) * 64;
  const ushort* pBm = pB + (size_t)mat * 2 * PS;
  // block-uniform compile-time-mode dispatch (R16 fix: no runtime mode)
  if (mat == 0)
    gemm_body<EPI, M0, KTOT>(A0, Ak2, pBm, C0, As, Bs, row0, col0, tid);
  else if (mat == 1)
    gemm_body<EPI, M1, KTOT>(A1, Ak2, pBm, C1, As, Bs, row0, col0, tid);
  else
    gemm_body<EPI, M2, KTOT>(A2, Ak2, pBm, C2, As, Bs, row0, col0, tid);
}

// ---------------------------------------------------------------------------
// Elementwise kernels
// ---------------------------------------------------------------------------
__device__ __forceinline__ float sigf(float z) { return 1.0f / (1.0f + expf(-z)); }

__global__ __launch_bounds__(256)
void gate_kernel(const float* __restrict__ x, const float* __restrict__ L,
                 const float* __restrict__ bg, float* __restrict__ out) {
  const int i4 = blockIdx.x * 256 + threadIdx.x;
  const float4 xv = ((const float4*)x)[i4];
  const float4 lv = ((const float4*)L)[i4];
  const float4 bv = ((const float4*)bg)[i4 & 255];
  float4 r;
  r.x = xv.x * (0.5f * sigf(lv.x + bv.x) + 0.5f);
  r.y = xv.y * (0.5f * sigf(lv.y + bv.y) + 0.5f);
  r.z = xv.z * (0.5f * sigf(lv.z + bv.z) + 0.5f);
  r.w = xv.w * (0.5f * sigf(lv.w + bv.w) + 0.5f);
  ((float4*)out)[i4] = r;
}

// modulated = a * (1 + tanh(c)) -> PRE-SPLIT planes.
__global__ __launch_bounds__(256)
void mod_kernel(const float* __restrict__ a, const float* __restrict__ c,
                ushort* __restrict__ pD) {
  const int i4 = blockIdx.x * 256 + threadIdx.x;
  const float4 av = ((const float4*)a)[i4];
  const float4 cv = ((const float4*)c)[i4];
  float r[4];
  r[0] = av.x * (1.0f + tanhf(cv.x));
  r[1] = av.y * (1.0f + tanhf(cv.y));
  r[2] = av.z * (1.0f + tanhf(cv.z));
  r[3] = av.w * (1.0f + tanhf(cv.w));
  uint p1[2], p2[2];
#pragma unroll
  for (int j = 0; j < 2; ++j) {
    ushort a1, a2, b1, b2;
    split2(r[2 * j], a1, a2);
    split2(r[2 * j + 1], b1, b2);
    p1[j] = (uint)a1 | ((uint)b1 << 16);
    p2[j] = (uint)a2 | ((uint)b2 << 16);
  }
  *(uint2*)(pD + (size_t)i4 * 4)         = *(uint2*)p1;
  *(uint2*)(pD + NELEM + (size_t)i4 * 4) = *(uint2*)p2;
}

// out = sigmoid(r) * wkv -> PRE-SPLIT planes.
__global__ __launch_bounds__(256)
void rmul_kernel(const float* __restrict__ rr, const float* __restrict__ wkv,
                 ushort* __restrict__ pD) {
  const int i4 = blockIdx.x * 256 + threadIdx.x;
  const float4 rv = ((const float4*)rr)[i4];
  const float4 wv = ((const float4*)wkv)[i4];
  float r[4];
  r[0] = sigf(rv.x) * wv.x;
  r[1] = sigf(rv.y) * wv.y;
  r[2] = sigf(rv.z) * wv.z;
  r[3] = sigf(rv.w) * wv.w;
  uint p1[2], p2[2];
#pragma unroll
  for (int j = 0; j < 2; ++j) {
    ushort a1, a2, b1, b2;
    split2(r[2 * j], a1, a2);
    split2(r[2 * j + 1], b1, b2);
    p1[j] = (uint)a1 | ((uint)b1 << 16);
    p2[j] = (uint)a2 | ((uint)b2 << 16);
  }
  *(uint2*)(pD + (size_t)i4 * 4)         = *(uint2*)p1;
  *(uint2*)(pD + NELEM + (size_t)i4 * 4) = *(uint2*)p2;
}

// ---------------------------------------------------------------------------
// LIF scans: bit-exact op order; 32-deep load pipeline (proven R15).
// ---------------------------------------------------------------------------
__global__ __launch_bounds__(64)
void lif_u8_kernel(const float* __restrict__ x, uint8_t* __restrict__ s) {
  const int c = blockIdx.x * 64 + threadIdx.x;
  const size_t off = (size_t)(c >> 10) * TDIM * DDIM + (c & 1023);
  const float* xp = x + off;
  uint8_t* sp = s + off;
  float u = 0.f;
  float cur[32];
#pragma unroll
  for (int i = 0; i < 32; ++i) cur[i] = xp[(size_t)i * DDIM];
  for (int t = 0; t < TDIM; t += 32) {
    float nxt[32];
    if (t + 32 < TDIM) {
#pragma unroll
      for (int i = 0; i < 32; ++i) nxt[i] = xp[(size_t)(t + 32 + i) * DDIM];
    }
#pragma unroll
    for (int i = 0; i < 32; ++i) {
      u = __fadd_rn(__fmul_rn(0.9f, u), cur[i]);
      const bool fire = (u >= 1.0f);
      sp[(size_t)(t + i) * DDIM] = fire ? 1 : 0;
      if (fire) u -= 1.0f;
    }
#pragma unroll
    for (int i = 0; i < 32; ++i) cur[i] = nxt[i];
  }
}

__global__ __launch_bounds__(64)
void lif_ip_kernel(float* __restrict__ x) {
  const int c = blockIdx.x * 64 + threadIdx.x;
  const size_t off = (size_t)(c >> 10) * TDIM * DDIM + (c & 1023);
  float* xp = x + off;
  float u = 0.f;
  float cur[32];
#pragma unroll
  for (int i = 0; i < 32; ++i) cur[i] = xp[(size_t)i * DDIM];
  for (int t = 0; t < TDIM; t += 32) {
    float nxt[32];
    if (t + 32 < TDIM) {
#pragma unroll
      for (int i = 0; i < 32; ++i) nxt[i] = xp[(size_t)(t + 32 + i) * DDIM];
    }
#pragma unroll
    for (int i = 0; i < 32; ++i) {
      u = __fadd_rn(__fmul_rn(0.9f, u), cur[i]);
      const float sv = (u >= 1.0f) ? 1.0f : 0.0f;
      xp[(size_t)(t + i) * DDIM] = sv;
      u -= sv;
    }
#pragma unroll
    for (int i = 0; i < 32; ++i) cur[i] = nxt[i];
  }
}

// ---------------------------------------------------------------------------
// RWKV recurrence: fast exp + rcp; 16-deep load pipeline (proven R15).
// ---------------------------------------------------------------------------
__global__ __launch_bounds__(64)
void rwkv_kernel(const float* __restrict__ k, const float* __restrict__ v,
                 const float* __restrict__ wd, const float* __restrict__ uf,
                 float* __restrict__ out) {
  const int c = blockIdx.x * 64 + threadIdx.x;
  const int d = c & 1023;
  const size_t off = (size_t)(c >> 10) * TDIM * DDIM + d;
  const float* kp = k + off;
  const float* vp = v + off;
  float* op = out + off;
  const float w = expf(wd[d]);
  const float u = uf[d];
  float aa = 0.f, bb = 0.f, pp = -1e30f;
  float kc[16], vc[16];
#pragma unroll
  for (int i = 0; i < 16; ++i) {
    kc[i] = kp[(size_t)i * DDIM];
    vc[i] = vp[(size_t)i * DDIM];
  }
  for (int t = 0; t < TDIM; t += 16) {
    float kn[16], vn[16];
    if (t + 16 < TDIM) {
#pragma unroll
      for (int i = 0; i < 16; ++i) {
        kn[i] = kp[(size_t)(t + 16 + i) * DDIM];
        vn[i] = vp[(size_t)(t + 16 + i) * DDIM];
      }
    }
#pragma unroll
    for (int i = 0; i < 16; ++i) {
      const float kt = kc[i], vt = vc[i];
      const float ww = __fadd_rn(u, kt);
      const float p  = fmaxf(pp, ww);
      float e1 = fexp(__fsub_rn(pp, p));
      float e2 = fexp(__fsub_rn(ww, p));
      const float num = __fadd_rn(__fmul_rn(e1, aa), __fmul_rn(e2, vt));
      const float den = __fadd_rn(__fmul_rn(e1, bb), e2);
      op[(size_t)(t + i) * DDIM] = num * __builtin_amdgcn_rcpf(den);
      const float ww2 = __fsub_rn(pp, w);
      const float p2  = fmaxf(ww2, kt);
      e1 = fexp(__fsub_rn(ww2, p2));
      e2 = fexp(__fsub_rn(kt, p2));
      aa = __fadd_rn(__fmul_rn(e1, aa), __fmul_rn(e2, vt));
      bb = __fadd_rn(__fmul_rn(e1, bb), e2);
      pp = p2;
    }
#pragma unroll
    for (int i = 0; i < 16; ++i) { kc[i] = kn[i]; vc[i] = vn[i]; }
  }
}

// ---------------------------------------------------------------------------
// MFMA flash attention — f16 2-plane split, Vt key-rotation swizzle, K/V
// global prefetch, fast-exp softmax; epilogue emits PRE-SPLIT O planes.
// ---------------------------------------------------------------------------
__global__ __launch_bounds__(256)
void flash_attn(const float* __restrict__ Q, const float* __restrict__ K,
                const float* __restrict__ V, ushort* __restrict__ pO) {
  __shared__ ushort Ks[2][32][136];    // [plane][key][kd]     17.4 KB
  __shared__ ushort Vt[2][128][40];    // [plane][d][key-slot] 20.5 KB
  __shared__ ushort Pl[4][2][16][40];  // [wave][plane][q][key] 10.2 KB
  const int tid = threadIdx.x;
  const int n    = blockIdx.x;
  const int xcd  = n & 7;
  const int idx  = n >> 3;
  const int qt   = idx & 15;
  const int grp4 = idx >> 4;
  const int p    = grp4 * 8 + xcd;
  const int b    = p >> 3, h = p & 7;
  const size_t base = ((size_t)b * TDIM) * DDIM + (size_t)h * DH;

  const int wave = tid >> 6;
  const int lane = tid & 63;
  const int lr   = lane & 15;
  const int g    = lane >> 4;
  const int sr   = tid >> 3;
  const int sc   = (tid & 7) * 16;
  const int vslot = (sr + 8 * (tid & 3)) & 31;   // rotated key slot

  // ---- prologue: Q -> register frags (2 planes x 4 ksteps) ----
  hfrag q1[4], q2[4];
  {
    const float* Qrow = Q + base + (size_t)(qt * 64 + wave * 16 + lr) * DDIM;
#pragma unroll
    for (int s = 0; s < 4; ++s) {
      const float4 f0 = *(const float4*)(Qrow + s * 32 + g * 8);
      const float4 f1 = *(const float4*)(Qrow + s * 32 + g * 8 + 4);
      const float qf[8] = {f0.x, f0.y, f0.z, f0.w, f1.x, f1.y, f1.z, f1.w};
      union { hfrag v; ushort u[8]; } u1, u2;
#pragma unroll
      for (int j = 0; j < 8; ++j) split2(qf[j], u1.u[j], u2.u[j]);
      q1[s] = u1.v; q2[s] = u2.v;
    }
  }

  facc oM[8], oS[8];
#pragma unroll
  for (int i = 0; i < 8; ++i) { oM[i] = (facc)0.f; oS[i] = (facc)0.f; }
  float m[4] = {-INFINITY, -INFINITY, -INFINITY, -INFINITY};
  float l[4] = {0.f, 0.f, 0.f, 0.f};
  const float ISC = 0.08838834764831845f;   // 1/sqrt(128)

  float kv[16], vv[16];
  auto gload = [&](int kt0) {
    const float* Kg = K + base + (size_t)(kt0 + sr) * DDIM + sc;
    const float* Vg = V + base + (size_t)(kt0 + sr) * DDIM + sc;
    *(float4*)&kv[0]  = *(const float4*)(Kg);
    *(float4*)&kv[4]  = *(const float4*)(Kg + 4);
    *(float4*)&kv[8]  = *(const float4*)(Kg + 8);
    *(float4*)&kv[12] = *(const float4*)(Kg + 12);
    *(float4*)&vv[0]  = *(const float4*)(Vg);
    *(float4*)&vv[4]  = *(const float4*)(Vg + 4);
    *(float4*)&vv[8]  = *(const float4*)(Vg + 8);
    *(float4*)&vv[12] = *(const float4*)(Vg + 12);
  };
  gload(0);

  for (int kt0 = 0; kt0 < TDIM; kt0 += 32) {
    __syncthreads();
    {
      uint w1[8], w2[8];
#pragma unroll
      for (int i = 0; i < 8; ++i) {
        ushort a1, a2, b1, b2;
        split2(kv[2 * i], a1, a2);
        split2(kv[2 * i + 1], b1, b2);
        w1[i] = (uint)a1 | ((uint)b1 << 16);
        w2[i] = (uint)a2 | ((uint)b2 << 16);
      }
      *(uint4*)&Ks[0][sr][sc]     = *(uint4*)&w1[0];
      *(uint4*)&Ks[0][sr][sc + 8] = *(uint4*)&w1[4];
      *(uint4*)&Ks[1][sr][sc]     = *(uint4*)&w2[0];
      *(uint4*)&Ks[1][sr][sc + 8] = *(uint4*)&w2[4];
#pragma unroll
      for (int i = 0; i < 16; ++i) {
        ushort a1, a2;
        split2(vv[i], a1, a2);
        Vt[0][sc + i][vslot] = a1;
        Vt[1][sc + i][vslot] = a2;
      }
    }
    if (kt0 + 32 < TDIM) gload(kt0 + 32);
    __syncthreads();

    // ---- QK^T: 3-pass split ----
    facc sM0 = (facc)0.f, sS0 = (facc)0.f, sM1 = (facc)0.f, sS1 = (facc)0.f;
#pragma unroll
    for (int s = 0; s < 4; ++s) {
      const int ko = s * 32 + g * 8;
      const hfrag kb10 = *(const hfrag*)&Ks[0][lr][ko];
      const hfrag kb11 = *(const hfrag*)&Ks[0][lr + 16][ko];
      const hfrag kb20 = *(const hfrag*)&Ks[1][lr][ko];
      const hfrag kb21 = *(const hfrag*)&Ks[1][lr + 16][ko];
      sM0 = __builtin_amdgcn_mfma_f32_16x16x32_f16(q1[s], kb10, sM0, 0, 0, 0);
      sS0 = __builtin_amdgcn_mfma_f32_16x16x32_f16(q1[s], kb20, sS0, 0, 0, 0);
      sS0 = __builtin_amdgcn_mfma_f32_16x16x32_f16(q2[s], kb10, sS0, 0, 0, 0);
      sM1 = __builtin_amdgcn_mfma_f32_16x16x32_f16(q1[s], kb11, sM1, 0, 0, 0);
      sS1 = __builtin_amdgcn_mfma_f32_16x16x32_f16(q1[s], kb21, sS1, 0, 0, 0);
      sS1 = __builtin_amdgcn_mfma_f32_16x16x32_f16(q2[s], kb11, sS1, 0, 0, 0);
    }

    // ---- online softmax (fast exp) ----
#pragma unroll
    for (int r = 0; r < 4; ++r) {
      const float sc0 = (sM0[r] + sS0[r] * INV2048) * ISC;
      const float sc1 = (sM1[r] + sS1[r] * INV2048) * ISC;
      float mx = fmaxf(sc0, sc1);
      mx = fmaxf(mx, __shfl_xor(mx, 1, 16));
      mx = fmaxf(mx, __shfl_xor(mx, 2, 16));
      mx = fmaxf(mx, __shfl_xor(mx, 4, 16));
      mx = fmaxf(mx, __shfl_xor(mx, 8, 16));
      const float mn = fmaxf(m[r], mx);
      const float rf = fexp(m[r] - mn);
      const float p0 = fexp(sc0 - mn), p1 = fexp(sc1 - mn);
      float ps = p0 + p1;
      ps += __shfl_xor(ps, 1, 16);
      ps += __shfl_xor(ps, 2, 16);
      ps += __shfl_xor(ps, 4, 16);
      ps += __shfl_xor(ps, 8, 16);
      l[r] = l[r] * rf + ps;
      m[r] = mn;
#pragma unroll
      for (int nf = 0; nf < 8; ++nf) { oM[nf][r] *= rf; oS[nf][r] *= rf; }
      ushort a1, a2;
      split2(p0, a1, a2);
      Pl[wave][0][g * 4 + r][lr] = a1;
      Pl[wave][1][g * 4 + r][lr] = a2;
      split2(p1, a1, a2);
      Pl[wave][0][g * 4 + r][lr + 16] = a1;
      Pl[wave][1][g * 4 + r][lr + 16] = a2;
    }

    // ---- PV ----
    const hfrag pa1 = *(const hfrag*)&Pl[wave][0][lr][g * 8];
    const hfrag pa2 = *(const hfrag*)&Pl[wave][1][lr][g * 8];
#pragma unroll
    for (int nf = 0; nf < 8; ++nf) {
      const int vs = 8 * ((g + nf) & 3);
      const hfrag vb1 = *(const hfrag*)&Vt[0][nf * 16 + lr][vs];
      const hfrag vb2 = *(const hfrag*)&Vt[1][nf * 16 + lr][vs];
      oM[nf] = __builtin_amdgcn_mfma_f32_16x16x32_f16(pa1, vb1, oM[nf], 0, 0, 0);
      oS[nf] = __builtin_amdgcn_mfma_f32_16x16x32_f16(pa1, vb2, oS[nf], 0, 0, 0);
      oS[nf] = __builtin_amdgcn_mfma_f32_16x16x32_f16(pa2, vb1, oS[nf], 0, 0, 0);
    }
  }

  // ---- epilogue: O/l -> pre-split planes ----
#pragma unroll
  for (int r = 0; r < 4; ++r) {
    const float invl = 1.0f / l[r];
    const size_t erow = base + (size_t)(qt * 64 + wave * 16 + g * 4 + r) * DDIM;
#pragma unroll
    for (int nf = 0; nf < 8; ++nf) {
      const float val = (oM[nf][r] + oS[nf][r] * INV2048) * invl;
      ushort h1, h2;
      split2(val, h1, h2);
      pO[erow + nf * 16 + lr]         = h1;
      pO[NELEM + erow + nf * 16 + lr] = h2;
    }
  }
}

// ---------------------------------------------------------------------------
// Final: y = lif2(f32) + spikes2(u8); LayerNorm; float32 store.
// ---------------------------------------------------------------------------
__global__ __launch_bounds__(256)
void ln_kernel(const float* __restrict__ a, const uint8_t* __restrict__ s8,
               const float* __restrict__ gamma, const float* __restrict__ beta,
               float* __restrict__ out) {
  const int row = blockIdx.x;
  const int tid = threadIdx.x;
  const size_t base = (size_t)row * DDIM;
  const float4 av = *(const float4*)(a + base + tid * 4);
  const uchar4 sv = *(const uchar4*)(s8 + base + tid * 4);
  const float y0 = av.x + (float)sv.x, y1 = av.y + (float)sv.y;
  const float y2 = av.z + (float)sv.z, y3 = av.w + (float)sv.w;
  float s = (y0 + y1) + (y2 + y3);
  float q = (y0 * y0 + y1 * y1) + (y2 * y2 + y3 * y3);
#pragma unroll
  for (int off = 1; off < 64; off <<= 1) {
    s += __shfl_xor(s, off);
    q += __shfl_xor(q, off);
  }
  __shared__ float red[8];
  const int wid = tid >> 6;
  if ((tid & 63) == 0) { red[wid * 2] = s; red[wid * 2 + 1] = q; }
  __syncthreads();
  const float ts = (red[0] + red[2]) + (red[4] + red[6]);
  const float tq = (red[1] + red[3]) + (red[5] + red[7]);
  const float mu  = ts * (1.0f / 1024.0f);
  const float var = tq * (1.0f / 1024.0f) - mu * mu;
  const float rs  = 1.0f / sqrtf(var + 1e-5f);
  const int d = tid * 4;
  const float4 gv  = *(const float4*)(gamma + d);
  const float4 btv = *(const float4*)(beta + d);
  float4 r;
  r.x = (y0 - mu) * rs * gv.x + btv.x;
  r.y = (y1 - mu) * rs * gv.y + btv.y;
  r.z = (y2 - mu) * rs * gv.z + btv.z;
  r.w = (y3 - mu) * rs * gv.w + btv.w;
  *(float4*)(out + base + d) = r;
}

// ---------------------------------------------------------------------------
// Workspace: 4 f32-sized slots (A,C,D,E) 67.1 MB + u8 spikes 4.2 MB +
// B planes 12 MB = 83.3 MB (ws_size >= 83.9 MB proven R1/R2).
// ---------------------------------------------------------------------------
extern "C" void kernel_launch(void* const* d_in, const int* in_sizes, int n_in,
                              void* d_out, int out_size, void* d_ws, size_t ws_size,
                              hipStream_t stream) {
  const float* x       = (const float*)d_in[0];
  const float* context = (const float*)d_in[1];
  const float* Wg  = (const float*)d_in[2];
  const float* bg  = (const float*)d_in[3];
  const float* Wc  = (const float*)d_in[4];
  const float* Wq  = (const float*)d_in[5];
  const float* Wk  = (const float*)d_in[6];
  const float* Wv  = (const float*)d_in[7];
  const float* Wo  = (const float*)d_in[8];
  const float* Wm  = (const float*)d_in[9];
  const float* rWk = (const float*)d_in[10];
  const float* rWv = (const float*)d_in[11];
  const float* rWr = (const float*)d_in[12];
  const float* rWo = (const float*)d_in[13];
  const float* wd  = (const float*)d_in[14];
  const float* uf  = (const float*)d_in[15];
  const float* gamma = (const float*)d_in[16];
  const float* beta  = (const float*)d_in[17];
  float* out = (float*)d_out;   // reference output dtype = float32

  float* w  = (float*)d_ws;
  float*   bA = w;
  float*   bC = w + 1 * NELEM;
  float*   bD = w + 2 * NELEM;
  float*   bE = w + 3 * NELEM;
  uint8_t* bS = (uint8_t*)(w + 4 * NELEM);                          // u8 spikes
  ushort*  pB = (ushort*)((uint8_t*)d_ws + 4 * NELEM * 4 + NELEM);  // B planes
  ushort*  pO = (ushort*)bE;   // flash-out planes (bE free until Wo GEMM)
  ushort*  pM = (ushort*)bD;   // modulated planes (bD free after flash)
  ushort*  pR = (ushort*)bD;   // sig(r)*wkv planes (bD free after kvr GEMM)

  const dim3 ew(4096);
  constexpr int M1 = 1024 * 1024;   // ushorts per 1024-K B plane

  // Stage 1: thalamic gate — single K=2048 GEMM over [x | context]
  cvt_h2t<<<dim3(16, 16, 2), 256, 0, stream>>>(Wg, Wc, nullptr, pB, 0, 1024, 2048);
  gemm_k<0, 0, 0, 0, 2048><<<512, 256, 0, stream>>>(x, nullptr, nullptr, context,
                                                    pB, bA, nullptr, nullptr);
  gate_kernel<<<ew, 256, 0, stream>>>(x, bA, bg, bA);
  // Stage 2: LIF -> spikes2 (u8)
  lif_u8_kernel<<<64, 64, 0, stream>>>(bA, bS);
  // Stage 3: spike self-attention — Q,K,V one N-merged u8 launch
  cvt_h2t<<<dim3(16, 16, 3), 256, 0, stream>>>(Wq, Wk, Wv, pB, 2 * M1, 0, 1024);
  gemm_k<0, 1, 1, 1, 1024><<<1536, 256, 0, stream>>>(bS, bS, bS, nullptr, pB,
                                                     bA, bC, bD);
  flash_attn<<<512, 256, 0, stream>>>(bA, bC, bD, pO);   // planes out
  // Stage 3.5 + 4: Wo (A=pO pre-split) and Wm (A=context f32) in ONE launch
  cvt_h2t<<<dim3(16, 16, 2), 256, 0, stream>>>(Wo, Wm, nullptr, pB, 2 * M1, 0, 1024);
  gemm_k<0, 2, 0, 0, 1024><<<1024, 256, 0, stream>>>(pO, context, nullptr, nullptr,
                                                     pB, bC, bA, nullptr);
  mod_kernel<<<ew, 256, 0, stream>>>(bC, bA, pM);        // modulated planes
  // Stage 5: RWKV — k,v,r one 3-way pre-split launch (shared A = pM)
  cvt_h2t<<<dim3(16, 16, 3), 256, 0, stream>>>(rWk, rWv, rWr, pB, 2 * M1, 0, 1024);
  gemm_k<0, 2, 2, 2, 1024><<<1536, 256, 0, stream>>>(pM, pM, pM, nullptr, pB,
                                                     bA, bC, bE);
  rwkv_kernel<<<64, 64, 0, stream>>>(bA, bC, wd, uf, bA);  // bA = wkv
  rmul_kernel<<<ew, 256, 0, stream>>>(bE, bA, pR);         // planes
  cvt_h2t<<<dim3(16, 16, 1), 256, 0, stream>>>(rWo, nullptr, nullptr, pB, 0, 0, 1024);
  gemm_k<0, 2, 2, 2, 1024><<<512, 256, 0, stream>>>(pR, nullptr, nullptr, nullptr,
                                                    pB, bC, nullptr, nullptr);
  // Stage 6: output LIF (in-place) + residual + LayerNorm
  lif_ip_kernel<<<64, 64, 0, stream>>>(bC);
  ln_kernel<<<4096, 256, 0, stream>>>(bC, bS, gamma, beta, out);
}

// Round 18
// 967.156 us; speedup vs baseline: 1.2944x; 1.2944x over previous
//
#include <hip/hip_runtime.h>
#include <hip/hip_bf16.h>
#include <math.h>

// Problem dims (fixed)
#define BDIM 4
#define TDIM 1024
#define DDIM 1024
#define DH   128
#define NELEM ((size_t)BDIM * TDIM * DDIM)   // 4,194,304

typedef __attribute__((ext_vector_type(8))) _Float16 hfrag;  // 8 f16 (4 VGPR)
typedef __attribute__((ext_vector_type(4))) float facc;      // 4 f32 acc

// f16 2-plane split: x = h1 + h2/2048 (22 mantissa bits). Proven R13-R15.
__device__ __forceinline__ void split2(float x, ushort& h1, ushort& h2) {
  const _Float16 a = (_Float16)x;
  const _Float16 b = (_Float16)((x - (float)a) * 2048.0f);
  union { _Float16 h; ushort u; } ua, ub;
  ua.h = a; ub.h = b;
  h1 = ua.u; h2 = ub.u;
}
#define INV2048 4.8828125e-4f    // 1/2048, exact

// Fast exp: v_exp_f32(x*log2e). Proven R14/R15.
__device__ __forceinline__ float fexp(float x) {
  return __builtin_amdgcn_exp2f(x * 1.4426950408889634f);
}

constexpr int GM = 4096, GN = 1024, GK = 1024;
constexpr int BM = 128, BK = 32;
constexpr int BKP = 40;                    // padded LDS k-dim (80 B rows)

// ---------------------------------------------------------------------------
// cvt_h2t: up to 3 weight matrices [1024][1024] f32 -> 2-plane f16 split,
// blocked-transposed [kTot/32][N=1024][32].
// ---------------------------------------------------------------------------
__global__ __launch_bounds__(256)
void cvt_h2t(const float* __restrict__ W0, const float* __restrict__ W1,
             const float* __restrict__ W2, ushort* __restrict__ P,
             int zstride, int zkoff, int kTot) {
  __shared__ float Ls[64][68];
  const int z = blockIdx.z;
  const float* W = (z == 0) ? W0 : (z == 1 ? W1 : W2);
  ushort* Pz = P + (size_t)z * zstride;
  const size_t PS = (size_t)kTot * GN;     // ushorts per plane
  const int t = threadIdx.x;
  const int k0 = blockIdx.x * 64, n0 = blockIdx.y * 64;
  const int r = t >> 4, c4 = (t & 15) << 2;
#pragma unroll
  for (int i = 0; i < 4; ++i)
    *(float4*)&Ls[r + i * 16][c4] =
        *(const float4*)(W + (size_t)(k0 + r + i * 16) * GN + n0 + c4);
  __syncthreads();
  const int n = t >> 2, kc = (t & 3) << 4;
  uint p1[8], p2[8];
#pragma unroll
  for (int jj = 0; jj < 8; ++jj) {
    const float x0 = Ls[kc + 2 * jj][n], x1 = Ls[kc + 2 * jj + 1][n];
    ushort a1, a2, b1, b2;
    split2(x0, a1, a2);
    split2(x1, b1, b2);
    p1[jj] = (uint)a1 | ((uint)b1 << 16);
    p2[jj] = (uint)a2 | ((uint)b2 << 16);
  }
  const int kk = k0 + kc + z * zkoff;
  ushort* d = Pz + (size_t)(kk >> 5) * (GN * 32) + (size_t)(n0 + n) * 32 + (kk & 31);
  *(uint4*)(d)          = *(uint4*)&p1[0];
  *(uint4*)(d + 8)      = *(uint4*)&p1[4];
  *(uint4*)(d + PS)     = *(uint4*)&p2[0];
  *(uint4*)(d + PS + 8) = *(uint4*)&p2[4];
}

// ---------------------------------------------------------------------------
// GEMM via 2-plane f16 MFMA (3 passes; AU8 spikes exact -> 2 passes).
// Tile 128x64, 4 waves, LDS 31 KB -> 3 blocks/CU. Uniform A-mode per launch
// (R16/R17 lesson: mixed/runtime modes -> scratch spill). Per-matrix A ptrs
// for N-merged launches; KTOT=2048 K-merges A (gate stage).
// GATE=1: fuse thalamic gate into the epilogue — v = x*(0.5*sig(v+bg)+0.5),
// identical op order & expf as the old gate_kernel (bit-identical output).
// ---------------------------------------------------------------------------
template<int EPI, int AU8, int KTOT, int GATE>
__global__ __launch_bounds__(256)
void gemm_k(const void* __restrict__ A0, const void* __restrict__ A1,
            const void* __restrict__ A2, const void* __restrict__ Ak2,
            const ushort* __restrict__ pB,
            float* __restrict__ C0, float* __restrict__ C1,
            float* __restrict__ C2,
            const float* __restrict__ xg, const float* __restrict__ bgv) {
  constexpr size_t PS = (size_t)KTOT * GN;   // ushorts per plane
  __shared__ ushort As[2][BM][BKP];
  __shared__ ushort Bs[2][64][BKP];
  const int tid = threadIdx.x;
  const int n   = blockIdx.x;
  const int xcd = n & 7;
  const int idx = n >> 3;
  const int by  = xcd * 4 + (idx & 3);
  const int bx  = idx >> 2;
  const int mat = bx >> 4;
  const int row0 = by * BM;
  const int col0 = (bx & 15) * 64;
  const ushort* pBm = pB + (size_t)mat * 2 * PS;
  float* C = (mat == 0) ? C0 : (mat == 1 ? C1 : C2);
  const void* Abase = (mat == 0) ? A0 : (mat == 1 ? A1 : A2);

  const int sm  = tid & 127;
  const int sk0 = (tid >> 7) << 4;

  const int wave = tid >> 6;
  const int lane = tid & 63;
  const int wrow = (wave >> 1) * 64;
  const int wcol = (wave & 1) * 32;
  const int lrow = lane & 15;
  const int kof  = (lane >> 4) * 8;

  facc accM[4][2], accS[4][2];
#pragma unroll
  for (int i = 0; i < 4; ++i)
#pragma unroll
    for (int j = 0; j < 2; ++j) { accM[i][j] = (facc)0.f; accS[i][j] = (facc)0.f; }

  float av[16];
  uint4 a8raw;
  uint4 bregs[2];

  auto gloadA = [&](int K0) {
    const void* src = Abase; int k = K0;
    if (KTOT > 1024 && K0 >= 1024) { src = Ak2; k = K0 - 1024; }
    if (AU8) {
      a8raw = *(const uint4*)((const uint8_t*)src + (size_t)(row0 + sm) * 1024 + k + sk0);
    } else {
      const float* Ap = (const float*)src + (size_t)(row0 + sm) * 1024 + k + sk0;
      *(float4*)&av[0]  = *(const float4*)(Ap);
      *(float4*)&av[4]  = *(const float4*)(Ap + 4);
      *(float4*)&av[8]  = *(const float4*)(Ap + 8);
      *(float4*)&av[12] = *(const float4*)(Ap + 12);
    }
  };
  auto gloadB = [&](int K0) {
    const int kb = K0 >> 5;
#pragma unroll
    for (int j = 0; j < 2; ++j) {
      const int u = tid + 256 * j;
      const int q = u & 3, nn = (u >> 2) & 63, p = u >> 8;
      bregs[j] = *(const uint4*)(pBm + (size_t)p * PS + (size_t)kb * (GN * 32)
                                 + (size_t)(col0 + nn) * 32 + q * 8);
    }
  };
  auto swrite = [&]() {
    if (AU8) {
      const uint w4[4] = {a8raw.x, a8raw.y, a8raw.z, a8raw.w};
      uint pk[8];
#pragma unroll
      for (int i = 0; i < 8; ++i) {
        const uint b0 = (w4[i >> 1] >> ((i & 1) * 16)) & 0xFFu;
        const uint b1 = (w4[i >> 1] >> ((i & 1) * 16 + 8)) & 0xFFu;
        pk[i] = (b0 * 0x3C00u) | ((b1 * 0x3C00u) << 16);   // f16 1.0 = 0x3C00
      }
      *(uint4*)&As[0][sm][sk0]     = *(uint4*)&pk[0];
      *(uint4*)&As[0][sm][sk0 + 8] = *(uint4*)&pk[4];
    } else {
      uint q1[8], q2[8];
#pragma unroll
      for (int i = 0; i < 8; ++i) {
        ushort a1, a2, b1, b2;
        split2(av[2 * i], a1, a2);
        split2(av[2 * i + 1], b1, b2);
        q1[i] = (uint)a1 | ((uint)b1 << 16);
        q2[i] = (uint)a2 | ((uint)b2 << 16);
      }
      *(uint4*)&As[0][sm][sk0]     = *(uint4*)&q1[0];
      *(uint4*)&As[0][sm][sk0 + 8] = *(uint4*)&q1[4];
      *(uint4*)&As[1][sm][sk0]     = *(uint4*)&q2[0];
      *(uint4*)&As[1][sm][sk0 + 8] = *(uint4*)&q2[4];
    }
#pragma unroll
    for (int j = 0; j < 2; ++j) {
      const int u = tid + 256 * j;
      const int q = u & 3, nn = (u >> 2) & 63, p = u >> 8;
      *(uint4*)&Bs[p][nn][q * 8] = bregs[j];
    }
  };

  gloadA(0); gloadB(0);
  for (int k0 = 0; k0 < KTOT; k0 += BK) {
    __syncthreads();
    swrite();
    const int kn = k0 + BK;
    if (kn < KTOT) { gloadA(kn); gloadB(kn); }
    __syncthreads();
    hfrag fb1[2], fb2[2];
#pragma unroll
    for (int f = 0; f < 2; ++f) {
      fb1[f] = *(const hfrag*)&Bs[0][wcol + f * 16 + lrow][kof];
      fb2[f] = *(const hfrag*)&Bs[1][wcol + f * 16 + lrow][kof];
    }
#pragma unroll
    for (int mi = 0; mi < 4; ++mi) {
      const hfrag a1 = *(const hfrag*)&As[0][wrow + mi * 16 + lrow][kof];
      hfrag a2;
      if (!AU8) a2 = *(const hfrag*)&As[1][wrow + mi * 16 + lrow][kof];
#pragma unroll
      for (int ni = 0; ni < 2; ++ni)
        accM[mi][ni] = __builtin_amdgcn_mfma_f32_16x16x32_f16(a1, fb1[ni], accM[mi][ni], 0, 0, 0);
#pragma unroll
      for (int ni = 0; ni < 2; ++ni) {
        accS[mi][ni] = __builtin_amdgcn_mfma_f32_16x16x32_f16(a1, fb2[ni], accS[mi][ni], 0, 0, 0);
        if (!AU8)
          accS[mi][ni] = __builtin_amdgcn_mfma_f32_16x16x32_f16(a2, fb1[ni], accS[mi][ni], 0, 0, 0);
      }
    }
  }

  // epilogue: D frag col = lane&15, row = (lane>>4)*4 + reg (m89/m91).
#pragma unroll
  for (int mi = 0; mi < 4; ++mi) {
#pragma unroll
    for (int ni = 0; ni < 2; ++ni) {
      const int rbase = row0 + wrow + mi * 16 + (lane >> 4) * 4;
      const int cc    = col0 + wcol + ni * 16 + lrow;
      float* cp = C + (size_t)rbase * GN + cc;
#pragma unroll
      for (int r = 0; r < 4; ++r) {
        float v = accM[mi][ni][r] + accS[mi][ni][r] * INV2048;
        if (EPI == 1) v += cp[(size_t)r * GN];
        if (GATE == 1) {
          // thalamic gate fused: same op order & expf as old gate_kernel
          const float xv = xg[(size_t)(rbase + r) * GN + cc];
          const float s  = 1.0f / (1.0f + expf(-(v + bgv[cc])));
          v = xv * (0.5f * s + 0.5f);
        }
        cp[(size_t)r * GN] = v;
      }
    }
  }
}

// ---------------------------------------------------------------------------
// Elementwise kernels
// ---------------------------------------------------------------------------
__device__ __forceinline__ float sigf(float z) { return 1.0f / (1.0f + expf(-z)); }

__global__ __launch_bounds__(256)
void mod_kernel(const float* __restrict__ a, const float* __restrict__ c,
                float* __restrict__ out) {
  const int i4 = blockIdx.x * 256 + threadIdx.x;
  const float4 av = ((const float4*)a)[i4];
  const float4 cv = ((const float4*)c)[i4];
  float4 r;
  r.x = av.x * (1.0f + tanhf(cv.x));
  r.y = av.y * (1.0f + tanhf(cv.y));
  r.z = av.z * (1.0f + tanhf(cv.z));
  r.w = av.w * (1.0f + tanhf(cv.w));
  ((float4*)out)[i4] = r;
}

__global__ __launch_bounds__(256)
void rmul_kernel(const float* __restrict__ rr, const float* __restrict__ wkv,
                 float* __restrict__ out) {
  const int i4 = blockIdx.x * 256 + threadIdx.x;
  const float4 rv = ((const float4*)rr)[i4];
  const float4 wv = ((const float4*)wkv)[i4];
  float4 r;
  r.x = sigf(rv.x) * wv.x;
  r.y = sigf(rv.y) * wv.y;
  r.z = sigf(rv.z) * wv.z;
  r.w = sigf(rv.w) * wv.w;
  ((float4*)out)[i4] = r;
}

// ---------------------------------------------------------------------------
// LIF scans: bit-exact op order; 32-deep load pipeline (proven R15).
// ---------------------------------------------------------------------------
__global__ __launch_bounds__(64)
void lif_u8_kernel(const float* __restrict__ x, uint8_t* __restrict__ s) {
  const int c = blockIdx.x * 64 + threadIdx.x;
  const size_t off = (size_t)(c >> 10) * TDIM * DDIM + (c & 1023);
  const float* xp = x + off;
  uint8_t* sp = s + off;
  float u = 0.f;
  float cur[32];
#pragma unroll
  for (int i = 0; i < 32; ++i) cur[i] = xp[(size_t)i * DDIM];
  for (int t = 0; t < TDIM; t += 32) {
    float nxt[32];
    if (t + 32 < TDIM) {
#pragma unroll
      for (int i = 0; i < 32; ++i) nxt[i] = xp[(size_t)(t + 32 + i) * DDIM];
    }
#pragma unroll
    for (int i = 0; i < 32; ++i) {
      u = __fadd_rn(__fmul_rn(0.9f, u), cur[i]);
      const bool fire = (u >= 1.0f);
      sp[(size_t)(t + i) * DDIM] = fire ? 1 : 0;
      if (fire) u -= 1.0f;
    }
#pragma unroll
    for (int i = 0; i < 32; ++i) cur[i] = nxt[i];
  }
}

__global__ __launch_bounds__(64)
void lif_ip_kernel(float* __restrict__ x) {
  const int c = blockIdx.x * 64 + threadIdx.x;
  const size_t off = (size_t)(c >> 10) * TDIM * DDIM + (c & 1023);
  float* xp = x + off;
  float u = 0.f;
  float cur[32];
#pragma unroll
  for (int i = 0; i < 32; ++i) cur[i] = xp[(size_t)i * DDIM];
  for (int t = 0; t < TDIM; t += 32) {
    float nxt[32];
    if (t + 32 < TDIM) {
#pragma unroll
      for (int i = 0; i < 32; ++i) nxt[i] = xp[(size_t)(t + 32 + i) * DDIM];
    }
#pragma unroll
    for (int i = 0; i < 32; ++i) {
      u = __fadd_rn(__fmul_rn(0.9f, u), cur[i]);
      const float sv = (u >= 1.0f) ? 1.0f : 0.0f;
      xp[(size_t)(t + i) * DDIM] = sv;
      u -= sv;
    }
#pragma unroll
    for (int i = 0; i < 32; ++i) cur[i] = nxt[i];
  }
}

// ---------------------------------------------------------------------------
// RWKV recurrence: fast exp + rcp; 16-deep load pipeline (proven R15).
// ---------------------------------------------------------------------------
__global__ __launch_bounds__(64)
void rwkv_kernel(const float* __restrict__ k, const float* __restrict__ v,
                 const float* __restrict__ wd, const float* __restrict__ uf,
                 float* __restrict__ out) {
  const int c = blockIdx.x * 64 + threadIdx.x;
  const int d = c & 1023;
  const size_t off = (size_t)(c >> 10) * TDIM * DDIM + d;
  const float* kp = k + off;
  const float* vp = v + off;
  float* op = out + off;
  const float w = expf(wd[d]);
  const float u = uf[d];
  float aa = 0.f, bb = 0.f, pp = -1e30f;
  float kc[16], vc[16];
#pragma unroll
  for (int i = 0; i < 16; ++i) {
    kc[i] = kp[(size_t)i * DDIM];
    vc[i] = vp[(size_t)i * DDIM];
  }
  for (int t = 0; t < TDIM; t += 16) {
    float kn[16], vn[16];
    if (t + 16 < TDIM) {
#pragma unroll
      for (int i = 0; i < 16; ++i) {
        kn[i] = kp[(size_t)(t + 16 + i) * DDIM];
        vn[i] = vp[(size_t)(t + 16 + i) * DDIM];
      }
    }
#pragma unroll
    for (int i = 0; i < 16; ++i) {
      const float kt = kc[i], vt = vc[i];
      const float ww = __fadd_rn(u, kt);
      const float p  = fmaxf(pp, ww);
      float e1 = fexp(__fsub_rn(pp, p));
      float e2 = fexp(__fsub_rn(ww, p));
      const float num = __fadd_rn(__fmul_rn(e1, aa), __fmul_rn(e2, vt));
      const float den = __fadd_rn(__fmul_rn(e1, bb), e2);
      op[(size_t)(t + i) * DDIM] = num * __builtin_amdgcn_rcpf(den);
      const float ww2 = __fsub_rn(pp, w);
      const float p2  = fmaxf(ww2, kt);
      e1 = fexp(__fsub_rn(ww2, p2));
      e2 = fexp(__fsub_rn(kt, p2));
      aa = __fadd_rn(__fmul_rn(e1, aa), __fmul_rn(e2, vt));
      bb = __fadd_rn(__fmul_rn(e1, bb), e2);
      pp = p2;
    }
#pragma unroll
    for (int i = 0; i < 16; ++i) { kc[i] = kn[i]; vc[i] = vn[i]; }
  }
}

// ---------------------------------------------------------------------------
// MFMA flash attention — f16 2-plane split (3 passes), Vt key-rotation
// swizzle + K/V global prefetch, fast-exp softmax (all proven R12-R15).
// O MAY ALIAS Q (Q consumed into regs in prologue; blocks own disjoint rows).
// ---------------------------------------------------------------------------
__global__ __launch_bounds__(256)
void flash_attn(const float* __restrict__ Q, const float* __restrict__ K,
                const float* __restrict__ V, float* __restrict__ O) {
  __shared__ ushort Ks[2][32][136];    // [plane][key][kd]     17.4 KB
  __shared__ ushort Vt[2][128][40];    // [plane][d][key-slot] 20.5 KB
  __shared__ ushort Pl[4][2][16][40];  // [wave][plane][q][key] 10.2 KB
  const int tid = threadIdx.x;
  const int n    = blockIdx.x;
  const int xcd  = n & 7;
  const int idx  = n >> 3;
  const int qt   = idx & 15;
  const int grp4 = idx >> 4;
  const int p    = grp4 * 8 + xcd;
  const int b    = p >> 3, h = p & 7;
  const size_t base = ((size_t)b * TDIM) * DDIM + (size_t)h * DH;

  const int wave = tid >> 6;
  const int lane = tid & 63;
  const int lr   = lane & 15;
  const int g    = lane >> 4;
  const int sr   = tid >> 3;
  const int sc   = (tid & 7) * 16;
  const int vslot = (sr + 8 * (tid & 3)) & 31;   // rotated key slot

  // ---- prologue: Q -> register frags (2 planes x 4 ksteps) ----
  hfrag q1[4], q2[4];
  {
    const float* Qrow = Q + base + (size_t)(qt * 64 + wave * 16 + lr) * DDIM;
#pragma unroll
    for (int s = 0; s < 4; ++s) {
      const float4 f0 = *(const float4*)(Qrow + s * 32 + g * 8);
      const float4 f1 = *(const float4*)(Qrow + s * 32 + g * 8 + 4);
      const float qf[8] = {f0.x, f0.y, f0.z, f0.w, f1.x, f1.y, f1.z, f1.w};
      union { hfrag v; ushort u[8]; } u1, u2;
#pragma unroll
      for (int j = 0; j < 8; ++j) split2(qf[j], u1.u[j], u2.u[j]);
      q1[s] = u1.v; q2[s] = u2.v;
    }
  }

  facc oM[8], oS[8];
#pragma unroll
  for (int i = 0; i < 8; ++i) { oM[i] = (facc)0.f; oS[i] = (facc)0.f; }
  float m[4] = {-INFINITY, -INFINITY, -INFINITY, -INFINITY};
  float l[4] = {0.f, 0.f, 0.f, 0.f};
  const float ISC = 0.08838834764831845f;   // 1/sqrt(128)

  float kv[16], vv[16];
  auto gload = [&](int kt0) {
    const float* Kg = K + base + (size_t)(kt0 + sr) * DDIM + sc;
    const float* Vg = V + base + (size_t)(kt0 + sr) * DDIM + sc;
    *(float4*)&kv[0]  = *(const float4*)(Kg);
    *(float4*)&kv[4]  = *(const float4*)(Kg + 4);
    *(float4*)&kv[8]  = *(const float4*)(Kg + 8);
    *(float4*)&kv[12] = *(const float4*)(Kg + 12);
    *(float4*)&vv[0]  = *(const float4*)(Vg);
    *(float4*)&vv[4]  = *(const float4*)(Vg + 4);
    *(float4*)&vv[8]  = *(const float4*)(Vg + 8);
    *(float4*)&vv[12] = *(const float4*)(Vg + 12);
  };
  gload(0);

  for (int kt0 = 0; kt0 < TDIM; kt0 += 32) {
    __syncthreads();
    {
      uint w1[8], w2[8];
#pragma unroll
      for (int i = 0; i < 8; ++i) {
        ushort a1, a2, b1, b2;
        split2(kv[2 * i], a1, a2);
        split2(kv[2 * i + 1], b1, b2);
        w1[i] = (uint)a1 | ((uint)b1 << 16);
        w2[i] = (uint)a2 | ((uint)b2 << 16);
      }
      *(uint4*)&Ks[0][sr][sc]     = *(uint4*)&w1[0];
      *(uint4*)&Ks[0][sr][sc + 8] = *(uint4*)&w1[4];
      *(uint4*)&Ks[1][sr][sc]     = *(uint4*)&w2[0];
      *(uint4*)&Ks[1][sr][sc + 8] = *(uint4*)&w2[4];
#pragma unroll
      for (int i = 0; i < 16; ++i) {
        ushort a1, a2;
        split2(vv[i], a1, a2);
        Vt[0][sc + i][vslot] = a1;
        Vt[1][sc + i][vslot] = a2;
      }
    }
    if (kt0 + 32 < TDIM) gload(kt0 + 32);
    __syncthreads();

    // ---- QK^T: 3-pass split ----
    facc sM0 = (facc)0.f, sS0 = (facc)0.f, sM1 = (facc)0.f, sS1 = (facc)0.f;
#pragma unroll
    for (int s = 0; s < 4; ++s) {
      const int ko = s * 32 + g * 8;
      const hfrag kb10 = *(const hfrag*)&Ks[0][lr][ko];
      const hfrag kb11 = *(const hfrag*)&Ks[0][lr + 16][ko];
      const hfrag kb20 = *(const hfrag*)&Ks[1][lr][ko];
      const hfrag kb21 = *(const hfrag*)&Ks[1][lr + 16][ko];
      sM0 = __builtin_amdgcn_mfma_f32_16x16x32_f16(q1[s], kb10, sM0, 0, 0, 0);
      sS0 = __builtin_amdgcn_mfma_f32_16x16x32_f16(q1[s], kb20, sS0, 0, 0, 0);
      sS0 = __builtin_amdgcn_mfma_f32_16x16x32_f16(q2[s], kb10, sS0, 0, 0, 0);
      sM1 = __builtin_amdgcn_mfma_f32_16x16x32_f16(q1[s], kb11, sM1, 0, 0, 0);
      sS1 = __builtin_amdgcn_mfma_f32_16x16x32_f16(q1[s], kb21, sS1, 0, 0, 0);
      sS1 = __builtin_amdgcn_mfma_f32_16x16x32_f16(q2[s], kb11, sS1, 0, 0, 0);
    }

    // ---- online softmax (fast exp) ----
#pragma unroll
    for (int r = 0; r < 4; ++r) {
      const float sc0 = (sM0[r] + sS0[r] * INV2048) * ISC;
      const float sc1 = (sM1[r] + sS1[r] * INV2048) * ISC;
      float mx = fmaxf(sc0, sc1);
      mx = fmaxf(mx, __shfl_xor(mx, 1, 16));
      mx = fmaxf(mx, __shfl_xor(mx, 2, 16));
      mx = fmaxf(mx, __shfl_xor(mx, 4, 16));
      mx = fmaxf(mx, __shfl_xor(mx, 8, 16));
      const float mn = fmaxf(m[r], mx);
      const float rf = fexp(m[r] - mn);       // exp2(-inf)=0 on first tile
      const float p0 = fexp(sc0 - mn), p1 = fexp(sc1 - mn);
      float ps = p0 + p1;
      ps += __shfl_xor(ps, 1, 16);
      ps += __shfl_xor(ps, 2, 16);
      ps += __shfl_xor(ps, 4, 16);
      ps += __shfl_xor(ps, 8, 16);
      l[r] = l[r] * rf + ps;
      m[r] = mn;
#pragma unroll
      for (int nf = 0; nf < 8; ++nf) { oM[nf][r] *= rf; oS[nf][r] *= rf; }
      ushort a1, a2;
      split2(p0, a1, a2);
      Pl[wave][0][g * 4 + r][lr] = a1;
      Pl[wave][1][g * 4 + r][lr] = a2;
      split2(p1, a1, a2);
      Pl[wave][0][g * 4 + r][lr + 16] = a1;
      Pl[wave][1][g * 4 + r][lr + 16] = a2;
    }

    // ---- PV ----
    const hfrag pa1 = *(const hfrag*)&Pl[wave][0][lr][g * 8];
    const hfrag pa2 = *(const hfrag*)&Pl[wave][1][lr][g * 8];
#pragma unroll
    for (int nf = 0; nf < 8; ++nf) {
      const int vs = 8 * ((g + nf) & 3);
      const hfrag vb1 = *(const hfrag*)&Vt[0][nf * 16 + lr][vs];
      const hfrag vb2 = *(const hfrag*)&Vt[1][nf * 16 + lr][vs];
      oM[nf] = __builtin_amdgcn_mfma_f32_16x16x32_f16(pa1, vb1, oM[nf], 0, 0, 0);
      oS[nf] = __builtin_amdgcn_mfma_f32_16x16x32_f16(pa1, vb2, oS[nf], 0, 0, 0);
      oS[nf] = __builtin_amdgcn_mfma_f32_16x16x32_f16(pa2, vb1, oS[nf], 0, 0, 0);
    }
  }

  // ---- epilogue ----
  float* Og = O + base + (size_t)(qt * 64 + wave * 16) * DDIM;
#pragma unroll
  for (int r = 0; r < 4; ++r) {
    const float invl = 1.0f / l[r];
    float* orow = Og + (size_t)(g * 4 + r) * DDIM;
#pragma unroll
    for (int nf = 0; nf < 8; ++nf)
      orow[nf * 16 + lr] = (oM[nf][r] + oS[nf][r] * INV2048) * invl;
  }
}

// ---------------------------------------------------------------------------
// Final: y = lif2(f32) + spikes2(u8); LayerNorm; float32 store.
// ---------------------------------------------------------------------------
__global__ __launch_bounds__(256)
void ln_kernel(const float* __restrict__ a, const uint8_t* __restrict__ s8,
               const float* __restrict__ gamma, const float* __restrict__ beta,
               float* __restrict__ out) {
  const int row = blockIdx.x;
  const int tid = threadIdx.x;
  const size_t base = (size_t)row * DDIM;
  const float4 av = *(const float4*)(a + base + tid * 4);
  const uchar4 sv = *(const uchar4*)(s8 + base + tid * 4);
  const float y0 = av.x + (float)sv.x, y1 = av.y + (float)sv.y;
  const float y2 = av.z + (float)sv.z, y3 = av.w + (float)sv.w;
  float s = (y0 + y1) + (y2 + y3);
  float q = (y0 * y0 + y1 * y1) + (y2 * y2 + y3 * y3);
#pragma unroll
  for (int off = 1; off < 64; off <<= 1) {
    s += __shfl_xor(s, off);
    q += __shfl_xor(q, off);
  }
  __shared__ float red[8];
  const int wid = tid >> 6;
  if ((tid & 63) == 0) { red[wid * 2] = s; red[wid * 2 + 1] = q; }
  __syncthreads();
  const float ts = (red[0] + red[2]) + (red[4] + red[6]);
  const float tq = (red[1] + red[3]) + (red[5] + red[7]);
  const float mu  = ts * (1.0f / 1024.0f);
  const float var = tq * (1.0f / 1024.0f) - mu * mu;
  const float rs  = 1.0f / sqrtf(var + 1e-5f);
  const int d = tid * 4;
  const float4 gv  = *(const float4*)(gamma + d);
  const float4 btv = *(const float4*)(beta + d);
  float4 r;
  r.x = (y0 - mu) * rs * gv.x + btv.x;
  r.y = (y1 - mu) * rs * gv.y + btv.y;
  r.z = (y2 - mu) * rs * gv.z + btv.z;
  r.w = (y3 - mu) * rs * gv.w + btv.w;
  *(float4*)(out + base + d) = r;
}

// ---------------------------------------------------------------------------
// Workspace: 4 f32 slots (A,C,D,E) 67.1 MB + u8 spikes 4.2 MB + B planes
// 12 MB = 83.3 MB (ws_size >= 83.9 MB proven R1/R2).
// ---------------------------------------------------------------------------
extern "C" void kernel_launch(void* const* d_in, const int* in_sizes, int n_in,
                              void* d_out, int out_size, void* d_ws, size_t ws_size,
                              hipStream_t stream) {
  const float* x       = (const float*)d_in[0];
  const float* context = (const float*)d_in[1];
  const float* Wg  = (const float*)d_in[2];
  const float* bg  = (const float*)d_in[3];
  const float* Wc  = (const float*)d_in[4];
  const float* Wq  = (const float*)d_in[5];
  const float* Wk  = (const float*)d_in[6];
  const float* Wv  = (const float*)d_in[7];
  const float* Wo  = (const float*)d_in[8];
  const float* Wm  = (const float*)d_in[9];
  const float* rWk = (const float*)d_in[10];
  const float* rWv = (const float*)d_in[11];
  const float* rWr = (const float*)d_in[12];
  const float* rWo = (const float*)d_in[13];
  const float* wd  = (const float*)d_in[14];
  const float* uf  = (const float*)d_in[15];
  const float* gamma = (const float*)d_in[16];
  const float* beta  = (const float*)d_in[17];
  float* out = (float*)d_out;   // reference output dtype = float32

  float* w  = (float*)d_ws;
  float*   bA = w;
  float*   bC = w + 1 * NELEM;
  float*   bD = w + 2 * NELEM;
  float*   bE = w + 3 * NELEM;
  uint8_t* bS = (uint8_t*)(w + 4 * NELEM);                          // u8 spikes
  ushort*  pB = (ushort*)((uint8_t*)d_ws + 4 * NELEM * 4 + NELEM);  // B planes

  const dim3 ew(4096);
  constexpr int M1 = 1024 * 1024;   // ushorts per 1024-K plane

  // Stage 1: thalamic gate — K=2048 GEMM over [x | context], gate FUSED
  cvt_h2t<<<dim3(16, 16, 2), 256, 0, stream>>>(Wg, Wc, nullptr, pB, 0, 1024, 2048);
  gemm_k<0, 0, 2048, 1><<<512, 256, 0, stream>>>(x, nullptr, nullptr, context,
                                                 pB, bA, nullptr, nullptr, x, bg);
  // Stage 2: LIF -> spikes2 (u8)
  lif_u8_kernel<<<64, 64, 0, stream>>>(bA, bS);
  // Stage 3: spike self-attention — Q,K,V one N-merged u8 launch
  cvt_h2t<<<dim3(16, 16, 3), 256, 0, stream>>>(Wq, Wk, Wv, pB, 2 * M1, 0, 1024);
  gemm_k<0, 1, 1024, 0><<<1536, 256, 0, stream>>>(bS, bS, bS, nullptr, pB,
                                                  bA, bC, bD, nullptr, nullptr);
  flash_attn<<<512, 256, 0, stream>>>(bA, bC, bD, bA);
  // Stage 3.5 + 4: Wo (A=attn_out) and Wm (A=context) in ONE launch
  cvt_h2t<<<dim3(16, 16, 2), 256, 0, stream>>>(Wo, Wm, nullptr, pB, 2 * M1, 0, 1024);
  gemm_k<0, 0, 1024, 0><<<1024, 256, 0, stream>>>(bA, context, nullptr, nullptr,
                                                  pB, bC, bE, nullptr,
                                                  nullptr, nullptr);
  mod_kernel<<<ew, 256, 0, stream>>>(bC, bE, bD);          // bD = modulated
  // Stage 5: RWKV — k,v,r one 3-way N-merged launch (shared A = bD)
  cvt_h2t<<<dim3(16, 16, 3), 256, 0, stream>>>(rWk, rWv, rWr, pB, 2 * M1, 0, 1024);
  gemm_k<0, 0, 1024, 0><<<1536, 256, 0, stream>>>(bD, bD, bD, nullptr, pB,
                                                  bA, bC, bE, nullptr, nullptr);
  rwkv_kernel<<<64, 64, 0, stream>>>(bA, bC, wd, uf, bA);  // bA = wkv
  rmul_kernel<<<ew, 256, 0, stream>>>(bE, bA, bA);         // bA = sig(r)*wkv
  cvt_h2t<<<dim3(16, 16, 1), 256, 0, stream>>>(rWo, nullptr, nullptr, pB, 0, 0, 1024);
  gemm_k<0, 0, 1024, 0><<<512, 256, 0, stream>>>(bA, nullptr, nullptr, nullptr,
                                                 pB, bC, nullptr, nullptr,
                                                 nullptr, nullptr);
  // Stage 6: output LIF (in-place) + residual + LayerNorm
  lif_ip_kernel<<<64, 64, 0, stream>>>(bC);
  ln_kernel<<<4096, 256, 0, stream>>>(bC, bS, gamma, beta, out);
}

// Round 19
// 966.056 us; speedup vs baseline: 1.2959x; 1.0011x over previous
//
#include <hip/hip_runtime.h>
#include <hip/hip_bf16.h>
#include <math.h>

// Problem dims (fixed)
#define BDIM 4
#define TDIM 1024
#define DDIM 1024
#define DH   128
#define NELEM ((size_t)BDIM * TDIM * DDIM)   // 4,194,304

typedef __attribute__((ext_vector_type(8))) _Float16 hfrag;  // 8 f16 (4 VGPR)
typedef __attribute__((ext_vector_type(4))) float facc;      // 4 f32 acc

// f16 2-plane split: x = h1 + h2/2048 (22 mantissa bits). Proven R13-R18.
__device__ __forceinline__ void split2(float x, ushort& h1, ushort& h2) {
  const _Float16 a = (_Float16)x;
  const _Float16 b = (_Float16)((x - (float)a) * 2048.0f);
  union { _Float16 h; ushort u; } ua, ub;
  ua.h = a; ub.h = b;
  h1 = ua.u; h2 = ub.u;
}
#define INV2048 4.8828125e-4f    // 1/2048, exact

// Fast exp: v_exp_f32(x*log2e). Proven R14-R18.
__device__ __forceinline__ float fexp(float x) {
  return __builtin_amdgcn_exp2f(x * 1.4426950408889634f);
}

constexpr int GM = 4096, GN = 1024, GK = 1024;
constexpr int BM = 128, BK = 32;
constexpr int BKP = 40;                    // padded LDS k-dim (80 B rows)

// ---------------------------------------------------------------------------
// cvt_h2t: up to 3 weight matrices [1024][1024] f32 -> 2-plane f16 split,
// blocked-transposed [kTot/32][N=1024][32].
// ---------------------------------------------------------------------------
__global__ __launch_bounds__(256)
void cvt_h2t(const float* __restrict__ W0, const float* __restrict__ W1,
             const float* __restrict__ W2, ushort* __restrict__ P,
             int zstride, int zkoff, int kTot) {
  __shared__ float Ls[64][68];
  const int z = blockIdx.z;
  const float* W = (z == 0) ? W0 : (z == 1 ? W1 : W2);
  ushort* Pz = P + (size_t)z * zstride;
  const size_t PS = (size_t)kTot * GN;     // ushorts per plane
  const int t = threadIdx.x;
  const int k0 = blockIdx.x * 64, n0 = blockIdx.y * 64;
  const int r = t >> 4, c4 = (t & 15) << 2;
#pragma unroll
  for (int i = 0; i < 4; ++i)
    *(float4*)&Ls[r + i * 16][c4] =
        *(const float4*)(W + (size_t)(k0 + r + i * 16) * GN + n0 + c4);
  __syncthreads();
  const int n = t >> 2, kc = (t & 3) << 4;
  uint p1[8], p2[8];
#pragma unroll
  for (int jj = 0; jj < 8; ++jj) {
    const float x0 = Ls[kc + 2 * jj][n], x1 = Ls[kc + 2 * jj + 1][n];
    ushort a1, a2, b1, b2;
    split2(x0, a1, a2);
    split2(x1, b1, b2);
    p1[jj] = (uint)a1 | ((uint)b1 << 16);
    p2[jj] = (uint)a2 | ((uint)b2 << 16);
  }
  const int kk = k0 + kc + z * zkoff;
  ushort* d = Pz + (size_t)(kk >> 5) * (GN * 32) + (size_t)(n0 + n) * 32 + (kk & 31);
  *(uint4*)(d)          = *(uint4*)&p1[0];
  *(uint4*)(d + 8)      = *(uint4*)&p1[4];
  *(uint4*)(d + PS)     = *(uint4*)&p2[0];
  *(uint4*)(d + PS + 8) = *(uint4*)&p2[4];
}

// ---------------------------------------------------------------------------
// GEMM via 2-plane f16 MFMA (3 passes; AU8 spikes exact -> 2 passes).
// Tile 128x64, 4 waves, LDS 31 KB. Uniform A-mode per launch (R16/R17
// lesson). This round: 2-DEEP register prefetch — loads for K-step k+2
// issued at step k (two named register sets, loop unrolled x2; no runtime
// set index -> no scratch). Gives each global load ~2 compute phases
// (~1000 cyc) to cover ~900 cyc HBM latency (R18 diagnosis: K-step
// latency-bound, MfmaUtil 16% with nothing saturated).
// GATE=1: thalamic gate fused in epilogue (bit-identical, proven R18).
// ---------------------------------------------------------------------------
template<int EPI, int AU8, int KTOT, int GATE>
__global__ __launch_bounds__(256)
void gemm_k(const void* __restrict__ A0, const void* __restrict__ A1,
            const void* __restrict__ A2, const void* __restrict__ Ak2,
            const ushort* __restrict__ pB,
            float* __restrict__ C0, float* __restrict__ C1,
            float* __restrict__ C2,
            const float* __restrict__ xg, const float* __restrict__ bgv) {
  constexpr size_t PS = (size_t)KTOT * GN;   // ushorts per plane
  __shared__ ushort As[2][BM][BKP];
  __shared__ ushort Bs[2][64][BKP];
  const int tid = threadIdx.x;
  const int n   = blockIdx.x;
  const int xcd = n & 7;
  const int idx = n >> 3;
  const int by  = xcd * 4 + (idx & 3);
  const int bx  = idx >> 2;
  const int mat = bx >> 4;
  const int row0 = by * BM;
  const int col0 = (bx & 15) * 64;
  const ushort* pBm = pB + (size_t)mat * 2 * PS;
  float* C = (mat == 0) ? C0 : (mat == 1 ? C1 : C2);
  const void* Abase = (mat == 0) ? A0 : (mat == 1 ? A1 : A2);

  const int sm  = tid & 127;
  const int sk0 = (tid >> 7) << 4;

  const int wave = tid >> 6;
  const int lane = tid & 63;
  const int wrow = (wave >> 1) * 64;
  const int wcol = (wave & 1) * 32;
  const int lrow = lane & 15;
  const int kof  = (lane >> 4) * 8;

  facc accM[4][2], accS[4][2];
#pragma unroll
  for (int i = 0; i < 4; ++i)
#pragma unroll
    for (int j = 0; j < 2; ++j) { accM[i][j] = (facc)0.f; accS[i][j] = (facc)0.f; }

  // two named prefetch sets (literal selection only — rule #20)
  float av0[16], av1[16];
  uint4 a80, a81;
  uint4 br0[2], br1[2];

  auto gloadA = [&](int K0, float* avd, uint4& a8d) {
    const void* src = Abase; int k = K0;
    if (KTOT > 1024 && K0 >= 1024) { src = Ak2; k = K0 - 1024; }
    if (AU8) {
      a8d = *(const uint4*)((const uint8_t*)src + (size_t)(row0 + sm) * 1024 + k + sk0);
    } else {
      const float* Ap = (const float*)src + (size_t)(row0 + sm) * 1024 + k + sk0;
      *(float4*)&avd[0]  = *(const float4*)(Ap);
      *(float4*)&avd[4]  = *(const float4*)(Ap + 4);
      *(float4*)&avd[8]  = *(const float4*)(Ap + 8);
      *(float4*)&avd[12] = *(const float4*)(Ap + 12);
    }
  };
  auto gloadB = [&](int K0, uint4* bd) {
    const int kb = K0 >> 5;
#pragma unroll
    for (int j = 0; j < 2; ++j) {
      const int u = tid + 256 * j;
      const int q = u & 3, nn = (u >> 2) & 63, p = u >> 8;
      bd[j] = *(const uint4*)(pBm + (size_t)p * PS + (size_t)kb * (GN * 32)
                              + (size_t)(col0 + nn) * 32 + q * 8);
    }
  };
  auto swrite = [&](const float* avs, const uint4& a8s, const uint4* bs) {
    if (AU8) {
      const uint w4[4] = {a8s.x, a8s.y, a8s.z, a8s.w};
      uint pk[8];
#pragma unroll
      for (int i = 0; i < 8; ++i) {
        const uint b0 = (w4[i >> 1] >> ((i & 1) * 16)) & 0xFFu;
        const uint b1 = (w4[i >> 1] >> ((i & 1) * 16 + 8)) & 0xFFu;
        pk[i] = (b0 * 0x3C00u) | ((b1 * 0x3C00u) << 16);   // f16 1.0 = 0x3C00
      }
      *(uint4*)&As[0][sm][sk0]     = *(uint4*)&pk[0];
      *(uint4*)&As[0][sm][sk0 + 8] = *(uint4*)&pk[4];
    } else {
      uint q1[8], q2[8];
#pragma unroll
      for (int i = 0; i < 8; ++i) {
        ushort a1, a2, b1, b2;
        split2(avs[2 * i], a1, a2);
        split2(avs[2 * i + 1], b1, b2);
        q1[i] = (uint)a1 | ((uint)b1 << 16);
        q2[i] = (uint)a2 | ((uint)b2 << 16);
      }
      *(uint4*)&As[0][sm][sk0]     = *(uint4*)&q1[0];
      *(uint4*)&As[0][sm][sk0 + 8] = *(uint4*)&q1[4];
      *(uint4*)&As[1][sm][sk0]     = *(uint4*)&q2[0];
      *(uint4*)&As[1][sm][sk0 + 8] = *(uint4*)&q2[4];
    }
#pragma unroll
    for (int j = 0; j < 2; ++j) {
      const int u = tid + 256 * j;
      const int q = u & 3, nn = (u >> 2) & 63, p = u >> 8;
      *(uint4*)&Bs[p][nn][q * 8] = bs[j];
    }
  };
  auto compute = [&]() {
    hfrag fb1[2], fb2[2];
#pragma unroll
    for (int f = 0; f < 2; ++f) {
      fb1[f] = *(const hfrag*)&Bs[0][wcol + f * 16 + lrow][kof];
      fb2[f] = *(const hfrag*)&Bs[1][wcol + f * 16 + lrow][kof];
    }
#pragma unroll
    for (int mi = 0; mi < 4; ++mi) {
      const hfrag a1 = *(const hfrag*)&As[0][wrow + mi * 16 + lrow][kof];
      hfrag a2;
      if (!AU8) a2 = *(const hfrag*)&As[1][wrow + mi * 16 + lrow][kof];
#pragma unroll
      for (int ni = 0; ni < 2; ++ni)
        accM[mi][ni] = __builtin_amdgcn_mfma_f32_16x16x32_f16(a1, fb1[ni], accM[mi][ni], 0, 0, 0);
#pragma unroll
      for (int ni = 0; ni < 2; ++ni) {
        accS[mi][ni] = __builtin_amdgcn_mfma_f32_16x16x32_f16(a1, fb2[ni], accS[mi][ni], 0, 0, 0);
        if (!AU8)
          accS[mi][ni] = __builtin_amdgcn_mfma_f32_16x16x32_f16(a2, fb1[ni], accS[mi][ni], 0, 0, 0);
      }
    }
  };

  // prologue: sets 0 and 1 in flight (K-steps 0 and BK)
  gloadA(0, av0, a80);  gloadB(0, br0);
  gloadA(BK, av1, a81); gloadB(BK, br1);
  for (int k0 = 0; k0 < KTOT; k0 += 2 * BK) {
    // step A (uses set0; refills set0 with k0+2BK)
    __syncthreads();
    swrite(av0, a80, br0);
    if (k0 + 2 * BK < KTOT) { gloadA(k0 + 2 * BK, av0, a80); gloadB(k0 + 2 * BK, br0); }
    __syncthreads();
    compute();
    // step B (uses set1; refills set1 with k0+3BK)
    __syncthreads();
    swrite(av1, a81, br1);
    if (k0 + 3 * BK < KTOT) { gloadA(k0 + 3 * BK, av1, a81); gloadB(k0 + 3 * BK, br1); }
    __syncthreads();
    compute();
  }

  // epilogue: D frag col = lane&15, row = (lane>>4)*4 + reg (m89/m91).
#pragma unroll
  for (int mi = 0; mi < 4; ++mi) {
#pragma unroll
    for (int ni = 0; ni < 2; ++ni) {
      const int rbase = row0 + wrow + mi * 16 + (lane >> 4) * 4;
      const int cc    = col0 + wcol + ni * 16 + lrow;
      float* cp = C + (size_t)rbase * GN + cc;
#pragma unroll
      for (int r = 0; r < 4; ++r) {
        float v = accM[mi][ni][r] + accS[mi][ni][r] * INV2048;
        if (EPI == 1) v += cp[(size_t)r * GN];
        if (GATE == 1) {
          // thalamic gate fused: same op order & expf as old gate_kernel
          const float xv = xg[(size_t)(rbase + r) * GN + cc];
          const float s  = 1.0f / (1.0f + expf(-(v + bgv[cc])));
          v = xv * (0.5f * s + 0.5f);
        }
        cp[(size_t)r * GN] = v;
      }
    }
  }
}

// ---------------------------------------------------------------------------
// Elementwise kernels
// ---------------------------------------------------------------------------
__device__ __forceinline__ float sigf(float z) { return 1.0f / (1.0f + expf(-z)); }

__global__ __launch_bounds__(256)
void mod_kernel(const float* __restrict__ a, const float* __restrict__ c,
                float* __restrict__ out) {
  const int i4 = blockIdx.x * 256 + threadIdx.x;
  const float4 av = ((const float4*)a)[i4];
  const float4 cv = ((const float4*)c)[i4];
  float4 r;
  r.x = av.x * (1.0f + tanhf(cv.x));
  r.y = av.y * (1.0f + tanhf(cv.y));
  r.z = av.z * (1.0f + tanhf(cv.z));
  r.w = av.w * (1.0f + tanhf(cv.w));
  ((float4*)out)[i4] = r;
}

__global__ __launch_bounds__(256)
void rmul_kernel(const float* __restrict__ rr, const float* __restrict__ wkv,
                 float* __restrict__ out) {
  const int i4 = blockIdx.x * 256 + threadIdx.x;
  const float4 rv = ((const float4*)rr)[i4];
  const float4 wv = ((const float4*)wkv)[i4];
  float4 r;
  r.x = sigf(rv.x) * wv.x;
  r.y = sigf(rv.y) * wv.y;
  r.z = sigf(rv.z) * wv.z;
  r.w = sigf(rv.w) * wv.w;
  ((float4*)out)[i4] = r;
}

// ---------------------------------------------------------------------------
// LIF scans: bit-exact op order; 32-deep load pipeline (proven R15).
// ---------------------------------------------------------------------------
__global__ __launch_bounds__(64)
void lif_u8_kernel(const float* __restrict__ x, uint8_t* __restrict__ s) {
  const int c = blockIdx.x * 64 + threadIdx.x;
  const size_t off = (size_t)(c >> 10) * TDIM * DDIM + (c & 1023);
  const float* xp = x + off;
  uint8_t* sp = s + off;
  float u = 0.f;
  float cur[32];
#pragma unroll
  for (int i = 0; i < 32; ++i) cur[i] = xp[(size_t)i * DDIM];
  for (int t = 0; t < TDIM; t += 32) {
    float nxt[32];
    if (t + 32 < TDIM) {
#pragma unroll
      for (int i = 0; i < 32; ++i) nxt[i] = xp[(size_t)(t + 32 + i) * DDIM];
    }
#pragma unroll
    for (int i = 0; i < 32; ++i) {
      u = __fadd_rn(__fmul_rn(0.9f, u), cur[i]);
      const bool fire = (u >= 1.0f);
      sp[(size_t)(t + i) * DDIM] = fire ? 1 : 0;
      if (fire) u -= 1.0f;
    }
#pragma unroll
    for (int i = 0; i < 32; ++i) cur[i] = nxt[i];
  }
}

__global__ __launch_bounds__(64)
void lif_ip_kernel(float* __restrict__ x) {
  const int c = blockIdx.x * 64 + threadIdx.x;
  const size_t off = (size_t)(c >> 10) * TDIM * DDIM + (c & 1023);
  float* xp = x + off;
  float u = 0.f;
  float cur[32];
#pragma unroll
  for (int i = 0; i < 32; ++i) cur[i] = xp[(size_t)i * DDIM];
  for (int t = 0; t < TDIM; t += 32) {
    float nxt[32];
    if (t + 32 < TDIM) {
#pragma unroll
      for (int i = 0; i < 32; ++i) nxt[i] = xp[(size_t)(t + 32 + i) * DDIM];
    }
#pragma unroll
    for (int i = 0; i < 32; ++i) {
      u = __fadd_rn(__fmul_rn(0.9f, u), cur[i]);
      const float sv = (u >= 1.0f) ? 1.0f : 0.0f;
      xp[(size_t)(t + i) * DDIM] = sv;
      u -= sv;
    }
#pragma unroll
    for (int i = 0; i < 32; ++i) cur[i] = nxt[i];
  }
}

// ---------------------------------------------------------------------------
// RWKV recurrence: fast exp + rcp; 16-deep load pipeline (proven R15).
// ---------------------------------------------------------------------------
__global__ __launch_bounds__(64)
void rwkv_kernel(const float* __restrict__ k, const float* __restrict__ v,
                 const float* __restrict__ wd, const float* __restrict__ uf,
                 float* __restrict__ out) {
  const int c = blockIdx.x * 64 + threadIdx.x;
  const int d = c & 1023;
  const size_t off = (size_t)(c >> 10) * TDIM * DDIM + d;
  const float* kp = k + off;
  const float* vp = v + off;
  float* op = out + off;
  const float w = expf(wd[d]);
  const float u = uf[d];
  float aa = 0.f, bb = 0.f, pp = -1e30f;
  float kc[16], vc[16];
#pragma unroll
  for (int i = 0; i < 16; ++i) {
    kc[i] = kp[(size_t)i * DDIM];
    vc[i] = vp[(size_t)i * DDIM];
  }
  for (int t = 0; t < TDIM; t += 16) {
    float kn[16], vn[16];
    if (t + 16 < TDIM) {
#pragma unroll
      for (int i = 0; i < 16; ++i) {
        kn[i] = kp[(size_t)(t + 16 + i) * DDIM];
        vn[i] = vp[(size_t)(t + 16 + i) * DDIM];
      }
    }
#pragma unroll
    for (int i = 0; i < 16; ++i) {
      const float kt = kc[i], vt = vc[i];
      const float ww = __fadd_rn(u, kt);
      const float p  = fmaxf(pp, ww);
      float e1 = fexp(__fsub_rn(pp, p));
      float e2 = fexp(__fsub_rn(ww, p));
      const float num = __fadd_rn(__fmul_rn(e1, aa), __fmul_rn(e2, vt));
      const float den = __fadd_rn(__fmul_rn(e1, bb), e2);
      op[(size_t)(t + i) * DDIM] = num * __builtin_amdgcn_rcpf(den);
      const float ww2 = __fsub_rn(pp, w);
      const float p2  = fmaxf(ww2, kt);
      e1 = fexp(__fsub_rn(ww2, p2));
      e2 = fexp(__fsub_rn(kt, p2));
      aa = __fadd_rn(__fmul_rn(e1, aa), __fmul_rn(e2, vt));
      bb = __fadd_rn(__fmul_rn(e1, bb), e2);
      pp = p2;
    }
#pragma unroll
    for (int i = 0; i < 16; ++i) { kc[i] = kn[i]; vc[i] = vn[i]; }
  }
}

// ---------------------------------------------------------------------------
// MFMA flash attention — f16 2-plane split (3 passes), Vt key-rotation
// swizzle + K/V global prefetch, fast-exp softmax (all proven R12-R18).
// O MAY ALIAS Q (Q consumed into regs in prologue; blocks own disjoint rows).
// ---------------------------------------------------------------------------
__global__ __launch_bounds__(256)
void flash_attn(const float* __restrict__ Q, const float* __restrict__ K,
                const float* __restrict__ V, float* __restrict__ O) {
  __shared__ ushort Ks[2][32][136];    // [plane][key][kd]     17.4 KB
  __shared__ ushort Vt[2][128][40];    // [plane][d][key-slot] 20.5 KB
  __shared__ ushort Pl[4][2][16][40];  // [wave][plane][q][key] 10.2 KB
  const int tid = threadIdx.x;
  const int n    = blockIdx.x;
  const int xcd  = n & 7;
  const int idx  = n >> 3;
  const int qt   = idx & 15;
  const int grp4 = idx >> 4;
  const int p    = grp4 * 8 + xcd;
  const int b    = p >> 3, h = p & 7;
  const size_t base = ((size_t)b * TDIM) * DDIM + (size_t)h * DH;

  const int wave = tid >> 6;
  const int lane = tid & 63;
  const int lr   = lane & 15;
  const int g    = lane >> 4;
  const int sr   = tid >> 3;
  const int sc   = (tid & 7) * 16;
  const int vslot = (sr + 8 * (tid & 3)) & 31;   // rotated key slot

  // ---- prologue: Q -> register frags (2 planes x 4 ksteps) ----
  hfrag q1[4], q2[4];
  {
    const float* Qrow = Q + base + (size_t)(qt * 64 + wave * 16 + lr) * DDIM;
#pragma unroll
    for (int s = 0; s < 4; ++s) {
      const float4 f0 = *(const float4*)(Qrow + s * 32 + g * 8);
      const float4 f1 = *(const float4*)(Qrow + s * 32 + g * 8 + 4);
      const float qf[8] = {f0.x, f0.y, f0.z, f0.w, f1.x, f1.y, f1.z, f1.w};
      union { hfrag v; ushort u[8]; } u1, u2;
#pragma unroll
      for (int j = 0; j < 8; ++j) split2(qf[j], u1.u[j], u2.u[j]);
      q1[s] = u1.v; q2[s] = u2.v;
    }
  }

  facc oM[8], oS[8];
#pragma unroll
  for (int i = 0; i < 8; ++i) { oM[i] = (facc)0.f; oS[i] = (facc)0.f; }
  float m[4] = {-INFINITY, -INFINITY, -INFINITY, -INFINITY};
  float l[4] = {0.f, 0.f, 0.f, 0.f};
  const float ISC = 0.08838834764831845f;   // 1/sqrt(128)

  float kv[16], vv[16];
  auto gload = [&](int kt0) {
    const float* Kg = K + base + (size_t)(kt0 + sr) * DDIM + sc;
    const float* Vg = V + base + (size_t)(kt0 + sr) * DDIM + sc;
    *(float4*)&kv[0]  = *(const float4*)(Kg);
    *(float4*)&kv[4]  = *(const float4*)(Kg + 4);
    *(float4*)&kv[8]  = *(const float4*)(Kg + 8);
    *(float4*)&kv[12] = *(const float4*)(Kg + 12);
    *(float4*)&vv[0]  = *(const float4*)(Vg);
    *(float4*)&vv[4]  = *(const float4*)(Vg + 4);
    *(float4*)&vv[8]  = *(const float4*)(Vg + 8);
    *(float4*)&vv[12] = *(const float4*)(Vg + 12);
  };
  gload(0);

  for (int kt0 = 0; kt0 < TDIM; kt0 += 32) {
    __syncthreads();
    {
      uint w1[8], w2[8];
#pragma unroll
      for (int i = 0; i < 8; ++i) {
        ushort a1, a2, b1, b2;
        split2(kv[2 * i], a1, a2);
        split2(kv[2 * i + 1], b1, b2);
        w1[i] = (uint)a1 | ((uint)b1 << 16);
        w2[i] = (uint)a2 | ((uint)b2 << 16);
      }
      *(uint4*)&Ks[0][sr][sc]     = *(uint4*)&w1[0];
      *(uint4*)&Ks[0][sr][sc + 8] = *(uint4*)&w1[4];
      *(uint4*)&Ks[1][sr][sc]     = *(uint4*)&w2[0];
      *(uint4*)&Ks[1][sr][sc + 8] = *(uint4*)&w2[4];
#pragma unroll
      for (int i = 0; i < 16; ++i) {
        ushort a1, a2;
        split2(vv[i], a1, a2);
        Vt[0][sc + i][vslot] = a1;
        Vt[1][sc + i][vslot] = a2;
      }
    }
    if (kt0 + 32 < TDIM) gload(kt0 + 32);
    __syncthreads();

    // ---- QK^T: 3-pass split ----
    facc sM0 = (facc)0.f, sS0 = (facc)0.f, sM1 = (facc)0.f, sS1 = (facc)0.f;
#pragma unroll
    for (int s = 0; s < 4; ++s) {
      const int ko = s * 32 + g * 8;
      const hfrag kb10 = *(const hfrag*)&Ks[0][lr][ko];
      const hfrag kb11 = *(const hfrag*)&Ks[0][lr + 16][ko];
      const hfrag kb20 = *(const hfrag*)&Ks[1][lr][ko];
      const hfrag kb21 = *(const hfrag*)&Ks[1][lr + 16][ko];
      sM0 = __builtin_amdgcn_mfma_f32_16x16x32_f16(q1[s], kb10, sM0, 0, 0, 0);
      sS0 = __builtin_amdgcn_mfma_f32_16x16x32_f16(q1[s], kb20, sS0, 0, 0, 0);
      sS0 = __builtin_amdgcn_mfma_f32_16x16x32_f16(q2[s], kb10, sS0, 0, 0, 0);
      sM1 = __builtin_amdgcn_mfma_f32_16x16x32_f16(q1[s], kb11, sM1, 0, 0, 0);
      sS1 = __builtin_amdgcn_mfma_f32_16x16x32_f16(q1[s], kb21, sS1, 0, 0, 0);
      sS1 = __builtin_amdgcn_mfma_f32_16x16x32_f16(q2[s], kb11, sS1, 0, 0, 0);
    }

    // ---- online softmax (fast exp) ----
#pragma unroll
    for (int r = 0; r < 4; ++r) {
      const float sc0 = (sM0[r] + sS0[r] * INV2048) * ISC;
      const float sc1 = (sM1[r] + sS1[r] * INV2048) * ISC;
      float mx = fmaxf(sc0, sc1);
      mx = fmaxf(mx, __shfl_xor(mx, 1, 16));
      mx = fmaxf(mx, __shfl_xor(mx, 2, 16));
      mx = fmaxf(mx, __shfl_xor(mx, 4, 16));
      mx = fmaxf(mx, __shfl_xor(mx, 8, 16));
      const float mn = fmaxf(m[r], mx);
      const float rf = fexp(m[r] - mn);       // exp2(-inf)=0 on first tile
      const float p0 = fexp(sc0 - mn), p1 = fexp(sc1 - mn);
      float ps = p0 + p1;
      ps += __shfl_xor(ps, 1, 16);
      ps += __shfl_xor(ps, 2, 16);
      ps += __shfl_xor(ps, 4, 16);
      ps += __shfl_xor(ps, 8, 16);
      l[r] = l[r] * rf + ps;
      m[r] = mn;
#pragma unroll
      for (int nf = 0; nf < 8; ++nf) { oM[nf][r] *= rf; oS[nf][r] *= rf; }
      ushort a1, a2;
      split2(p0, a1, a2);
      Pl[wave][0][g * 4 + r][lr] = a1;
      Pl[wave][1][g * 4 + r][lr] = a2;
      split2(p1, a1, a2);
      Pl[wave][0][g * 4 + r][lr + 16] = a1;
      Pl[wave][1][g * 4 + r][lr + 16] = a2;
    }

    // ---- PV ----
    const hfrag pa1 = *(const hfrag*)&Pl[wave][0][lr][g * 8];
    const hfrag pa2 = *(const hfrag*)&Pl[wave][1][lr][g * 8];
#pragma unroll
    for (int nf = 0; nf < 8; ++nf) {
      const int vs = 8 * ((g + nf) & 3);
      const hfrag vb1 = *(const hfrag*)&Vt[0][nf * 16 + lr][vs];
      const hfrag vb2 = *(const hfrag*)&Vt[1][nf * 16 + lr][vs];
      oM[nf] = __builtin_amdgcn_mfma_f32_16x16x32_f16(pa1, vb1, oM[nf], 0, 0, 0);
      oS[nf] = __builtin_amdgcn_mfma_f32_16x16x32_f16(pa1, vb2, oS[nf], 0, 0, 0);
      oS[nf] = __builtin_amdgcn_mfma_f32_16x16x32_f16(pa2, vb1, oS[nf], 0, 0, 0);
    }
  }

  // ---- epilogue ----
  float* Og = O + base + (size_t)(qt * 64 + wave * 16) * DDIM;
#pragma unroll
  for (int r = 0; r < 4; ++r) {
    const float invl = 1.0f / l[r];
    float* orow = Og + (size_t)(g * 4 + r) * DDIM;
#pragma unroll
    for (int nf = 0; nf < 8; ++nf)
      orow[nf * 16 + lr] = (oM[nf][r] + oS[nf][r] * INV2048) * invl;
  }
}

// ---------------------------------------------------------------------------
// Final: y = lif2(f32) + spikes2(u8); LayerNorm; float32 store.
// ---------------------------------------------------------------------------
__global__ __launch_bounds__(256)
void ln_kernel(const float* __restrict__ a, const uint8_t* __restrict__ s8,
               const float* __restrict__ gamma, const float* __restrict__ beta,
               float* __restrict__ out) {
  const int row = blockIdx.x;
  const int tid = threadIdx.x;
  const size_t base = (size_t)row * DDIM;
  const float4 av = *(const float4*)(a + base + tid * 4);
  const uchar4 sv = *(const uchar4*)(s8 + base + tid * 4);
  const float y0 = av.x + (float)sv.x, y1 = av.y + (float)sv.y;
  const float y2 = av.z + (float)sv.z, y3 = av.w + (float)sv.w;
  float s = (y0 + y1) + (y2 + y3);
  float q = (y0 * y0 + y1 * y1) + (y2 * y2 + y3 * y3);
#pragma unroll
  for (int off = 1; off < 64; off <<= 1) {
    s += __shfl_xor(s, off);
    q += __shfl_xor(q, off);
  }
  __shared__ float red[8];
  const int wid = tid >> 6;
  if ((tid & 63) == 0) { red[wid * 2] = s; red[wid * 2 + 1] = q; }
  __syncthreads();
  const float ts = (red[0] + red[2]) + (red[4] + red[6]);
  const float tq = (red[1] + red[3]) + (red[5] + red[7]);
  const float mu  = ts * (1.0f / 1024.0f);
  const float var = tq * (1.0f / 1024.0f) - mu * mu;
  const float rs  = 1.0f / sqrtf(var + 1e-5f);
  const int d = tid * 4;
  const float4 gv  = *(const float4*)(gamma + d);
  const float4 btv = *(const float4*)(beta + d);
  float4 r;
  r.x = (y0 - mu) * rs * gv.x + btv.x;
  r.y = (y1 - mu) * rs * gv.y + btv.y;
  r.z = (y2 - mu) * rs * gv.z + btv.z;
  r.w = (y3 - mu) * rs * gv.w + btv.w;
  *(float4*)(out + base + d) = r;
}

// ---------------------------------------------------------------------------
// Workspace: 4 f32 slots (A,C,D,E) 67.1 MB + u8 spikes 4.2 MB + B planes
// 12 MB = 83.3 MB (ws_size >= 83.9 MB proven R1/R2).
// ---------------------------------------------------------------------------
extern "C" void kernel_launch(void* const* d_in, const int* in_sizes, int n_in,
                              void* d_out, int out_size, void* d_ws, size_t ws_size,
                              hipStream_t stream) {
  const float* x       = (const float*)d_in[0];
  const float* context = (const float*)d_in[1];
  const float* Wg  = (const float*)d_in[2];
  const float* bg  = (const float*)d_in[3];
  const float* Wc  = (const float*)d_in[4];
  const float* Wq  = (const float*)d_in[5];
  const float* Wk  = (const float*)d_in[6];
  const float* Wv  = (const float*)d_in[7];
  const float* Wo  = (const float*)d_in[8];
  const float* Wm  = (const float*)d_in[9];
  const float* rWk = (const float*)d_in[10];
  const float* rWv = (const float*)d_in[11];
  const float* rWr = (const float*)d_in[12];
  const float* rWo = (const float*)d_in[13];
  const float* wd  = (const float*)d_in[14];
  const float* uf  = (const float*)d_in[15];
  const float* gamma = (const float*)d_in[16];
  const float* beta  = (const float*)d_in[17];
  float* out = (float*)d_out;   // reference output dtype = float32

  float* w  = (float*)d_ws;
  float*   bA = w;
  float*   bC = w + 1 * NELEM;
  float*   bD = w + 2 * NELEM;
  float*   bE = w + 3 * NELEM;
  uint8_t* bS = (uint8_t*)(w + 4 * NELEM);                          // u8 spikes
  ushort*  pB = (ushort*)((uint8_t*)d_ws + 4 * NELEM * 4 + NELEM);  // B planes

  const dim3 ew(4096);
  constexpr int M1 = 1024 * 1024;   // ushorts per 1024-K plane

  // Stage 1: thalamic gate — K=2048 GEMM over [x | context], gate FUSED
  cvt_h2t<<<dim3(16, 16, 2), 256, 0, stream>>>(Wg, Wc, nullptr, pB, 0, 1024, 2048);
  gemm_k<0, 0, 2048, 1><<<512, 256, 0, stream>>>(x, nullptr, nullptr, context,
                                                 pB, bA, nullptr, nullptr, x, bg);
  // Stage 2: LIF -> spikes2 (u8)
  lif_u8_kernel<<<64, 64, 0, stream>>>(bA, bS);
  // Stage 3: spike self-attention — Q,K,V one N-merged u8 launch
  cvt_h2t<<<dim3(16, 16, 3), 256, 0, stream>>>(Wq, Wk, Wv, pB, 2 * M1, 0, 1024);
  gemm_k<0, 1, 1024, 0><<<1536, 256, 0, stream>>>(bS, bS, bS, nullptr, pB,
                                                  bA, bC, bD, nullptr, nullptr);
  flash_attn<<<512, 256, 0, stream>>>(bA, bC, bD, bA);
  // Stage 3.5 + 4: Wo (A=attn_out) and Wm (A=context) in ONE launch
  cvt_h2t<<<dim3(16, 16, 2), 256, 0, stream>>>(Wo, Wm, nullptr, pB, 2 * M1, 0, 1024);
  gemm_k<0, 0, 1024, 0><<<1024, 256, 0, stream>>>(bA, context, nullptr, nullptr,
                                                  pB, bC, bE, nullptr,
                                                  nullptr, nullptr);
  mod_kernel<<<ew, 256, 0, stream>>>(bC, bE, bD);          // bD = modulated
  // Stage 5: RWKV — k,v,r one 3-way N-merged launch (shared A = bD)
  cvt_h2t<<<dim3(16, 16, 3), 256, 0, stream>>>(rWk, rWv, rWr, pB, 2 * M1, 0, 1024);
  gemm_k<0, 0, 1024, 0><<<1536, 256, 0, stream>>>(bD, bD, bD, nullptr, pB,
                                                  bA, bC, bE, nullptr, nullptr);
  rwkv_kernel<<<64, 64, 0, stream>>>(bA, bC, wd, uf, bA);  // bA = wkv
  rmul_kernel<<<ew, 256, 0, stream>>>(bE, bA, bA);         // bA = sig(r)*wkv
  cvt_h2t<<<dim3(16, 16, 1), 256, 0, stream>>>(rWo, nullptr, nullptr, pB, 0, 0, 1024);
  gemm_k<0, 0, 1024, 0><<<512, 256, 0, stream>>>(bA, nullptr, nullptr, nullptr,
                                                 pB, bC, nullptr, nullptr,
                                                 nullptr, nullptr);
  // Stage 6: output LIF (in-place) + residual + LayerNorm
  lif_ip_kernel<<<64, 64, 0, stream>>>(bC);
  ln_kernel<<<4096, 256, 0, stream>>>(bC, bS, gamma, beta, out);
}

// Round 20
// 862.237 us; speedup vs baseline: 1.4519x; 1.1204x over previous
//
#include <hip/hip_runtime.h>
#include <hip/hip_bf16.h>
#include <math.h>

// Problem dims (fixed)
#define BDIM 4
#define TDIM 1024
#define DDIM 1024
#define DH   128
#define NELEM ((size_t)BDIM * TDIM * DDIM)   // 4,194,304

typedef __attribute__((ext_vector_type(8))) _Float16 hfrag;  // 8 f16 (4 VGPR)
typedef __attribute__((ext_vector_type(4))) float facc;      // 4 f32 acc

// f16 2-plane split: x = h1 + h2/2048 (22 mantissa bits). Proven R13-R19.
__device__ __forceinline__ void split2(float x, ushort& h1, ushort& h2) {
  const _Float16 a = (_Float16)x;
  const _Float16 b = (_Float16)((x - (float)a) * 2048.0f);
  union { _Float16 h; ushort u; } ua, ub;
  ua.h = a; ub.h = b;
  h1 = ua.u; h2 = ub.u;
}
#define INV2048 4.8828125e-4f    // 1/2048, exact

// Fast exp: v_exp_f32(x*log2e). Proven R14-R19.
__device__ __forceinline__ float fexp(float x) {
  return __builtin_amdgcn_exp2f(x * 1.4426950408889634f);
}

constexpr int GM = 4096, GN = 1024, GK = 1024;
constexpr int BM = 128, BK = 32;
constexpr int BKP = 40;                    // padded LDS k-dim (80 B rows)

// ---------------------------------------------------------------------------
// cvt_h2t: up to 3 weight matrices [1024][1024] f32 -> 2-plane f16 split,
// blocked-transposed [kTot/32][N=1024][32].
// ---------------------------------------------------------------------------
__global__ __launch_bounds__(256)
void cvt_h2t(const float* __restrict__ W0, const float* __restrict__ W1,
             const float* __restrict__ W2, ushort* __restrict__ P,
             int zstride, int zkoff, int kTot) {
  __shared__ float Ls[64][68];
  const int z = blockIdx.z;
  const float* W = (z == 0) ? W0 : (z == 1 ? W1 : W2);
  ushort* Pz = P + (size_t)z * zstride;
  const size_t PS = (size_t)kTot * GN;     // ushorts per plane
  const int t = threadIdx.x;
  const int k0 = blockIdx.x * 64, n0 = blockIdx.y * 64;
  const int r = t >> 4, c4 = (t & 15) << 2;
#pragma unroll
  for (int i = 0; i < 4; ++i)
    *(float4*)&Ls[r + i * 16][c4] =
        *(const float4*)(W + (size_t)(k0 + r + i * 16) * GN + n0 + c4);
  __syncthreads();
  const int n = t >> 2, kc = (t & 3) << 4;
  uint p1[8], p2[8];
#pragma unroll
  for (int jj = 0; jj < 8; ++jj) {
    const float x0 = Ls[kc + 2 * jj][n], x1 = Ls[kc + 2 * jj + 1][n];
    ushort a1, a2, b1, b2;
    split2(x0, a1, a2);
    split2(x1, b1, b2);
    p1[jj] = (uint)a1 | ((uint)b1 << 16);
    p2[jj] = (uint)a2 | ((uint)b2 << 16);
  }
  const int kk = k0 + kc + z * zkoff;
  ushort* d = Pz + (size_t)(kk >> 5) * (GN * 32) + (size_t)(n0 + n) * 32 + (kk & 31);
  *(uint4*)(d)          = *(uint4*)&p1[0];
  *(uint4*)(d + 8)      = *(uint4*)&p1[4];
  *(uint4*)(d + PS)     = *(uint4*)&p2[0];
  *(uint4*)(d + PS + 8) = *(uint4*)&p2[4];
}

// ---------------------------------------------------------------------------
// GEMM via 2-plane f16 MFMA (3 passes; AU8 spikes exact -> 2 passes).
// Tile 128x64, 4 waves. R20: LDS DOUBLE-BUFFER -> ONE barrier per K-step
// (R19 disproved load-latency binding; the 2nd barrier drain was the cost).
// compute(buf[k&1]) while staging k+1 into buf[k&1^1]; gloads for k+2
// issued before compute. LDS 61 KB -> 2 blocks/CU (~= measured occupancy).
// Single register prefetch set (R19's 2-deep was neutral + spilled).
// GATE=1: thalamic gate fused in epilogue (bit-identical, proven R18).
// ---------------------------------------------------------------------------
template<int EPI, int AU8, int KTOT, int GATE>
__global__ __launch_bounds__(256)
void gemm_k(const void* __restrict__ A0, const void* __restrict__ A1,
            const void* __restrict__ A2, const void* __restrict__ Ak2,
            const ushort* __restrict__ pB,
            float* __restrict__ C0, float* __restrict__ C1,
            float* __restrict__ C2,
            const float* __restrict__ xg, const float* __restrict__ bgv) {
  constexpr size_t PS = (size_t)KTOT * GN;   // ushorts per plane
  __shared__ ushort As[2][2][BM][BKP];       // [buf][plane][row][k]  41 KB
  __shared__ ushort Bs[2][2][64][BKP];       // [buf][plane][col][k]  20 KB
  const int tid = threadIdx.x;
  const int n   = blockIdx.x;
  const int xcd = n & 7;
  const int idx = n >> 3;
  const int by  = xcd * 4 + (idx & 3);
  const int bx  = idx >> 2;
  const int mat = bx >> 4;
  const int row0 = by * BM;
  const int col0 = (bx & 15) * 64;
  const ushort* pBm = pB + (size_t)mat * 2 * PS;
  float* C = (mat == 0) ? C0 : (mat == 1 ? C1 : C2);
  const void* Abase = (mat == 0) ? A0 : (mat == 1 ? A1 : A2);

  const int sm  = tid & 127;
  const int sk0 = (tid >> 7) << 4;

  const int wave = tid >> 6;
  const int lane = tid & 63;
  const int wrow = (wave >> 1) * 64;
  const int wcol = (wave & 1) * 32;
  const int lrow = lane & 15;
  const int kof  = (lane >> 4) * 8;

  facc accM[4][2], accS[4][2];
#pragma unroll
  for (int i = 0; i < 4; ++i)
#pragma unroll
    for (int j = 0; j < 2; ++j) { accM[i][j] = (facc)0.f; accS[i][j] = (facc)0.f; }

  float av[16];
  uint4 a8raw;
  uint4 bregs[2];

  auto gloadA = [&](int K0) {
    const void* src = Abase; int k = K0;
    if (KTOT > 1024 && K0 >= 1024) { src = Ak2; k = K0 - 1024; }
    if (AU8) {
      a8raw = *(const uint4*)((const uint8_t*)src + (size_t)(row0 + sm) * 1024 + k + sk0);
    } else {
      const float* Ap = (const float*)src + (size_t)(row0 + sm) * 1024 + k + sk0;
      *(float4*)&av[0]  = *(const float4*)(Ap);
      *(float4*)&av[4]  = *(const float4*)(Ap + 4);
      *(float4*)&av[8]  = *(const float4*)(Ap + 8);
      *(float4*)&av[12] = *(const float4*)(Ap + 12);
    }
  };
  auto gloadB = [&](int K0) {
    const int kb = K0 >> 5;
#pragma unroll
    for (int j = 0; j < 2; ++j) {
      const int u = tid + 256 * j;
      const int q = u & 3, nn = (u >> 2) & 63, p = u >> 8;
      bregs[j] = *(const uint4*)(pBm + (size_t)p * PS + (size_t)kb * (GN * 32)
                                 + (size_t)(col0 + nn) * 32 + q * 8);
    }
  };
  auto swrite = [&](int bi) {
    if (AU8) {
      const uint w4[4] = {a8raw.x, a8raw.y, a8raw.z, a8raw.w};
      uint pk[8];
#pragma unroll
      for (int i = 0; i < 8; ++i) {
        const uint b0 = (w4[i >> 1] >> ((i & 1) * 16)) & 0xFFu;
        const uint b1 = (w4[i >> 1] >> ((i & 1) * 16 + 8)) & 0xFFu;
        pk[i] = (b0 * 0x3C00u) | ((b1 * 0x3C00u) << 16);   // f16 1.0 = 0x3C00
      }
      *(uint4*)&As[bi][0][sm][sk0]     = *(uint4*)&pk[0];
      *(uint4*)&As[bi][0][sm][sk0 + 8] = *(uint4*)&pk[4];
    } else {
      uint q1[8], q2[8];
#pragma unroll
      for (int i = 0; i < 8; ++i) {
        ushort a1, a2, b1, b2;
        split2(av[2 * i], a1, a2);
        split2(av[2 * i + 1], b1, b2);
        q1[i] = (uint)a1 | ((uint)b1 << 16);
        q2[i] = (uint)a2 | ((uint)b2 << 16);
      }
      *(uint4*)&As[bi][0][sm][sk0]     = *(uint4*)&q1[0];
      *(uint4*)&As[bi][0][sm][sk0 + 8] = *(uint4*)&q1[4];
      *(uint4*)&As[bi][1][sm][sk0]     = *(uint4*)&q2[0];
      *(uint4*)&As[bi][1][sm][sk0 + 8] = *(uint4*)&q2[4];
    }
#pragma unroll
    for (int j = 0; j < 2; ++j) {
      const int u = tid + 256 * j;
      const int q = u & 3, nn = (u >> 2) & 63, p = u >> 8;
      *(uint4*)&Bs[bi][p][nn][q * 8] = bregs[j];
    }
  };
  auto compute = [&](int bi) {
    hfrag fb1[2], fb2[2];
#pragma unroll
    for (int f = 0; f < 2; ++f) {
      fb1[f] = *(const hfrag*)&Bs[bi][0][wcol + f * 16 + lrow][kof];
      fb2[f] = *(const hfrag*)&Bs[bi][1][wcol + f * 16 + lrow][kof];
    }
#pragma unroll
    for (int mi = 0; mi < 4; ++mi) {
      const hfrag a1 = *(const hfrag*)&As[bi][0][wrow + mi * 16 + lrow][kof];
      hfrag a2;
      if (!AU8) a2 = *(const hfrag*)&As[bi][1][wrow + mi * 16 + lrow][kof];
#pragma unroll
      for (int ni = 0; ni < 2; ++ni)
        accM[mi][ni] = __builtin_amdgcn_mfma_f32_16x16x32_f16(a1, fb1[ni], accM[mi][ni], 0, 0, 0);
#pragma unroll
      for (int ni = 0; ni < 2; ++ni) {
        accS[mi][ni] = __builtin_amdgcn_mfma_f32_16x16x32_f16(a1, fb2[ni], accS[mi][ni], 0, 0, 0);
        if (!AU8)
          accS[mi][ni] = __builtin_amdgcn_mfma_f32_16x16x32_f16(a2, fb1[ni], accS[mi][ni], 0, 0, 0);
      }
    }
  };

  // prologue: stage tile 0 into buf0; tile 1 loads in regs; one barrier
  constexpr int NK = KTOT / BK;
  gloadA(0); gloadB(0);
  swrite(0);
  gloadA(BK); gloadB(BK);
  __syncthreads();
  for (int ks = 0; ks < NK; ++ks) {
    const int cur = ks & 1;
    if (ks + 1 < NK) swrite(cur ^ 1);           // stage tile ks+1 (buffer free:
                                                // its readers retired at the
                                                // barrier ending iter ks-1)
    if (ks + 2 < NK) { gloadA((ks + 2) * BK); gloadB((ks + 2) * BK); }
    compute(cur);
    __syncthreads();                            // ONE barrier per K-step
  }

  // epilogue: D frag col = lane&15, row = (lane>>4)*4 + reg (m89/m91).
#pragma unroll
  for (int mi = 0; mi < 4; ++mi) {
#pragma unroll
    for (int ni = 0; ni < 2; ++ni) {
      const int rbase = row0 + wrow + mi * 16 + (lane >> 4) * 4;
      const int cc    = col0 + wcol + ni * 16 + lrow;
      float* cp = C + (size_t)rbase * GN + cc;
#pragma unroll
      for (int r = 0; r < 4; ++r) {
        float v = accM[mi][ni][r] + accS[mi][ni][r] * INV2048;
        if (EPI == 1) v += cp[(size_t)r * GN];
        if (GATE == 1) {
          // thalamic gate fused: same op order & expf as old gate_kernel
          const float xv = xg[(size_t)(rbase + r) * GN + cc];
          const float s  = 1.0f / (1.0f + expf(-(v + bgv[cc])));
          v = xv * (0.5f * s + 0.5f);
        }
        cp[(size_t)r * GN] = v;
      }
    }
  }
}

// ---------------------------------------------------------------------------
// Elementwise kernels
// ---------------------------------------------------------------------------
__device__ __forceinline__ float sigf(float z) { return 1.0f / (1.0f + expf(-z)); }

__global__ __launch_bounds__(256)
void mod_kernel(const float* __restrict__ a, const float* __restrict__ c,
                float* __restrict__ out) {
  const int i4 = blockIdx.x * 256 + threadIdx.x;
  const float4 av = ((const float4*)a)[i4];
  const float4 cv = ((const float4*)c)[i4];
  float4 r;
  r.x = av.x * (1.0f + tanhf(cv.x));
  r.y = av.y * (1.0f + tanhf(cv.y));
  r.z = av.z * (1.0f + tanhf(cv.z));
  r.w = av.w * (1.0f + tanhf(cv.w));
  ((float4*)out)[i4] = r;
}

__global__ __launch_bounds__(256)
void rmul_kernel(const float* __restrict__ rr, const float* __restrict__ wkv,
                 float* __restrict__ out) {
  const int i4 = blockIdx.x * 256 + threadIdx.x;
  const float4 rv = ((const float4*)rr)[i4];
  const float4 wv = ((const float4*)wkv)[i4];
  float4 r;
  r.x = sigf(rv.x) * wv.x;
  r.y = sigf(rv.y) * wv.y;
  r.z = sigf(rv.z) * wv.z;
  r.w = sigf(rv.w) * wv.w;
  ((float4*)out)[i4] = r;
}

// ---------------------------------------------------------------------------
// LIF scans: bit-exact op order; 32-deep load pipeline (proven R15).
// ---------------------------------------------------------------------------
__global__ __launch_bounds__(64)
void lif_u8_kernel(const float* __restrict__ x, uint8_t* __restrict__ s) {
  const int c = blockIdx.x * 64 + threadIdx.x;
  const size_t off = (size_t)(c >> 10) * TDIM * DDIM + (c & 1023);
  const float* xp = x + off;
  uint8_t* sp = s + off;
  float u = 0.f;
  float cur[32];
#pragma unroll
  for (int i = 0; i < 32; ++i) cur[i] = xp[(size_t)i * DDIM];
  for (int t = 0; t < TDIM; t += 32) {
    float nxt[32];
    if (t + 32 < TDIM) {
#pragma unroll
      for (int i = 0; i < 32; ++i) nxt[i] = xp[(size_t)(t + 32 + i) * DDIM];
    }
#pragma unroll
    for (int i = 0; i < 32; ++i) {
      u = __fadd_rn(__fmul_rn(0.9f, u), cur[i]);
      const bool fire = (u >= 1.0f);
      sp[(size_t)(t + i) * DDIM] = fire ? 1 : 0;
      if (fire) u -= 1.0f;
    }
#pragma unroll
    for (int i = 0; i < 32; ++i) cur[i] = nxt[i];
  }
}

__global__ __launch_bounds__(64)
void lif_ip_kernel(float* __restrict__ x) {
  const int c = blockIdx.x * 64 + threadIdx.x;
  const size_t off = (size_t)(c >> 10) * TDIM * DDIM + (c & 1023);
  float* xp = x + off;
  float u = 0.f;
  float cur[32];
#pragma unroll
  for (int i = 0; i < 32; ++i) cur[i] = xp[(size_t)i * DDIM];
  for (int t = 0; t < TDIM; t += 32) {
    float nxt[32];
    if (t + 32 < TDIM) {
#pragma unroll
      for (int i = 0; i < 32; ++i) nxt[i] = xp[(size_t)(t + 32 + i) * DDIM];
    }
#pragma unroll
    for (int i = 0; i < 32; ++i) {
      u = __fadd_rn(__fmul_rn(0.9f, u), cur[i]);
      const float sv = (u >= 1.0f) ? 1.0f : 0.0f;
      xp[(size_t)(t + i) * DDIM] = sv;
      u -= sv;
    }
#pragma unroll
    for (int i = 0; i < 32; ++i) cur[i] = nxt[i];
  }
}

// ---------------------------------------------------------------------------
// RWKV recurrence: fast exp + rcp; 16-deep load pipeline (proven R15).
// ---------------------------------------------------------------------------
__global__ __launch_bounds__(64)
void rwkv_kernel(const float* __restrict__ k, const float* __restrict__ v,
                 const float* __restrict__ wd, const float* __restrict__ uf,
                 float* __restrict__ out) {
  const int c = blockIdx.x * 64 + threadIdx.x;
  const int d = c & 1023;
  const size_t off = (size_t)(c >> 10) * TDIM * DDIM + d;
  const float* kp = k + off;
  const float* vp = v + off;
  float* op = out + off;
  const float w = expf(wd[d]);
  const float u = uf[d];
  float aa = 0.f, bb = 0.f, pp = -1e30f;
  float kc[16], vc[16];
#pragma unroll
  for (int i = 0; i < 16; ++i) {
    kc[i] = kp[(size_t)i * DDIM];
    vc[i] = vp[(size_t)i * DDIM];
  }
  for (int t = 0; t < TDIM; t += 16) {
    float kn[16], vn[16];
    if (t + 16 < TDIM) {
#pragma unroll
      for (int i = 0; i < 16; ++i) {
        kn[i] = kp[(size_t)(t + 16 + i) * DDIM];
        vn[i] = vp[(size_t)(t + 16 + i) * DDIM];
      }
    }
#pragma unroll
    for (int i = 0; i < 16; ++i) {
      const float kt = kc[i], vt = vc[i];
      const float ww = __fadd_rn(u, kt);
      const float p  = fmaxf(pp, ww);
      float e1 = fexp(__fsub_rn(pp, p));
      float e2 = fexp(__fsub_rn(ww, p));
      const float num = __fadd_rn(__fmul_rn(e1, aa), __fmul_rn(e2, vt));
      const float den = __fadd_rn(__fmul_rn(e1, bb), e2);
      op[(size_t)(t + i) * DDIM] = num * __builtin_amdgcn_rcpf(den);
      const float ww2 = __fsub_rn(pp, w);
      const float p2  = fmaxf(ww2, kt);
      e1 = fexp(__fsub_rn(ww2, p2));
      e2 = fexp(__fsub_rn(kt, p2));
      aa = __fadd_rn(__fmul_rn(e1, aa), __fmul_rn(e2, vt));
      bb = __fadd_rn(__fmul_rn(e1, bb), e2);
      pp = p2;
    }
#pragma unroll
    for (int i = 0; i < 16; ++i) { kc[i] = kn[i]; vc[i] = vn[i]; }
  }
}

// ---------------------------------------------------------------------------
// MFMA flash attention — f16 2-plane split (3 passes), Vt key-rotation
// swizzle + K/V global prefetch, fast-exp softmax (all proven R12-R19).
// O MAY ALIAS Q (Q consumed into regs in prologue; blocks own disjoint rows).
// ---------------------------------------------------------------------------
__global__ __launch_bounds__(256)
void flash_attn(const float* __restrict__ Q, const float* __restrict__ K,
                const float* __restrict__ V, float* __restrict__ O) {
  __shared__ ushort Ks[2][32][136];    // [plane][key][kd]     17.4 KB
  __shared__ ushort Vt[2][128][40];    // [plane][d][key-slot] 20.5 KB
  __shared__ ushort Pl[4][2][16][40];  // [wave][plane][q][key] 10.2 KB
  const int tid = threadIdx.x;
  const int n    = blockIdx.x;
  const int xcd  = n & 7;
  const int idx  = n >> 3;
  const int qt   = idx & 15;
  const int grp4 = idx >> 4;
  const int p    = grp4 * 8 + xcd;
  const int b    = p >> 3, h = p & 7;
  const size_t base = ((size_t)b * TDIM) * DDIM + (size_t)h * DH;

  const int wave = tid >> 6;
  const int lane = tid & 63;
  const int lr   = lane & 15;
  const int g    = lane >> 4;
  const int sr   = tid >> 3;
  const int sc   = (tid & 7) * 16;
  const int vslot = (sr + 8 * (tid & 3)) & 31;   // rotated key slot

  // ---- prologue: Q -> register frags (2 planes x 4 ksteps) ----
  hfrag q1[4], q2[4];
  {
    const float* Qrow = Q + base + (size_t)(qt * 64 + wave * 16 + lr) * DDIM;
#pragma unroll
    for (int s = 0; s < 4; ++s) {
      const float4 f0 = *(const float4*)(Qrow + s * 32 + g * 8);
      const float4 f1 = *(const float4*)(Qrow + s * 32 + g * 8 + 4);
      const float qf[8] = {f0.x, f0.y, f0.z, f0.w, f1.x, f1.y, f1.z, f1.w};
      union { hfrag v; ushort u[8]; } u1, u2;
#pragma unroll
      for (int j = 0; j < 8; ++j) split2(qf[j], u1.u[j], u2.u[j]);
      q1[s] = u1.v; q2[s] = u2.v;
    }
  }

  facc oM[8], oS[8];
#pragma unroll
  for (int i = 0; i < 8; ++i) { oM[i] = (facc)0.f; oS[i] = (facc)0.f; }
  float m[4] = {-INFINITY, -INFINITY, -INFINITY, -INFINITY};
  float l[4] = {0.f, 0.f, 0.f, 0.f};
  const float ISC = 0.08838834764831845f;   // 1/sqrt(128)

  float kv[16], vv[16];
  auto gload = [&](int kt0) {
    const float* Kg = K + base + (size_t)(kt0 + sr) * DDIM + sc;
    const float* Vg = V + base + (size_t)(kt0 + sr) * DDIM + sc;
    *(float4*)&kv[0]  = *(const float4*)(Kg);
    *(float4*)&kv[4]  = *(const float4*)(Kg + 4);
    *(float4*)&kv[8]  = *(const float4*)(Kg + 8);
    *(float4*)&kv[12] = *(const float4*)(Kg + 12);
    *(float4*)&vv[0]  = *(const float4*)(Vg);
    *(float4*)&vv[4]  = *(const float4*)(Vg + 4);
    *(float4*)&vv[8]  = *(const float4*)(Vg + 8);
    *(float4*)&vv[12] = *(const float4*)(Vg + 12);
  };
  gload(0);

  for (int kt0 = 0; kt0 < TDIM; kt0 += 32) {
    __syncthreads();
    {
      uint w1[8], w2[8];
#pragma unroll
      for (int i = 0; i < 8; ++i) {
        ushort a1, a2, b1, b2;
        split2(kv[2 * i], a1, a2);
        split2(kv[2 * i + 1], b1, b2);
        w1[i] = (uint)a1 | ((uint)b1 << 16);
        w2[i] = (uint)a2 | ((uint)b2 << 16);
      }
      *(uint4*)&Ks[0][sr][sc]     = *(uint4*)&w1[0];
      *(uint4*)&Ks[0][sr][sc + 8] = *(uint4*)&w1[4];
      *(uint4*)&Ks[1][sr][sc]     = *(uint4*)&w2[0];
      *(uint4*)&Ks[1][sr][sc + 8] = *(uint4*)&w2[4];
#pragma unroll
      for (int i = 0; i < 16; ++i) {
        ushort a1, a2;
        split2(vv[i], a1, a2);
        Vt[0][sc + i][vslot] = a1;
        Vt[1][sc + i][vslot] = a2;
      }
    }
    if (kt0 + 32 < TDIM) gload(kt0 + 32);
    __syncthreads();

    // ---- QK^T: 3-pass split ----
    facc sM0 = (facc)0.f, sS0 = (facc)0.f, sM1 = (facc)0.f, sS1 = (facc)0.f;
#pragma unroll
    for (int s = 0; s < 4; ++s) {
      const int ko = s * 32 + g * 8;
      const hfrag kb10 = *(const hfrag*)&Ks[0][lr][ko];
      const hfrag kb11 = *(const hfrag*)&Ks[0][lr + 16][ko];
      const hfrag kb20 = *(const hfrag*)&Ks[1][lr][ko];
      const hfrag kb21 = *(const hfrag*)&Ks[1][lr + 16][ko];
      sM0 = __builtin_amdgcn_mfma_f32_16x16x32_f16(q1[s], kb10, sM0, 0, 0, 0);
      sS0 = __builtin_amdgcn_mfma_f32_16x16x32_f16(q1[s], kb20, sS0, 0, 0, 0);
      sS0 = __builtin_amdgcn_mfma_f32_16x16x32_f16(q2[s], kb10, sS0, 0, 0, 0);
      sM1 = __builtin_amdgcn_mfma_f32_16x16x32_f16(q1[s], kb11, sM1, 0, 0, 0);
      sS1 = __builtin_amdgcn_mfma_f32_16x16x32_f16(q1[s], kb21, sS1, 0, 0, 0);
      sS1 = __builtin_amdgcn_mfma_f32_16x16x32_f16(q2[s], kb11, sS1, 0, 0, 0);
    }

    // ---- online softmax (fast exp) ----
#pragma unroll
    for (int r = 0; r < 4; ++r) {
      const float sc0 = (sM0[r] + sS0[r] * INV2048) * ISC;
      const float sc1 = (sM1[r] + sS1[r] * INV2048) * ISC;
      float mx = fmaxf(sc0, sc1);
      mx = fmaxf(mx, __shfl_xor(mx, 1, 16));
      mx = fmaxf(mx, __shfl_xor(mx, 2, 16));
      mx = fmaxf(mx, __shfl_xor(mx, 4, 16));
      mx = fmaxf(mx, __shfl_xor(mx, 8, 16));
      const float mn = fmaxf(m[r], mx);
      const float rf = fexp(m[r] - mn);       // exp2(-inf)=0 on first tile
      const float p0 = fexp(sc0 - mn), p1 = fexp(sc1 - mn);
      float ps = p0 + p1;
      ps += __shfl_xor(ps, 1, 16);
      ps += __shfl_xor(ps, 2, 16);
      ps += __shfl_xor(ps, 4, 16);
      ps += __shfl_xor(ps, 8, 16);
      l[r] = l[r] * rf + ps;
      m[r] = mn;
#pragma unroll
      for (int nf = 0; nf < 8; ++nf) { oM[nf][r] *= rf; oS[nf][r] *= rf; }
      ushort a1, a2;
      split2(p0, a1, a2);
      Pl[wave][0][g * 4 + r][lr] = a1;
      Pl[wave][1][g * 4 + r][lr] = a2;
      split2(p1, a1, a2);
      Pl[wave][0][g * 4 + r][lr + 16] = a1;
      Pl[wave][1][g * 4 + r][lr + 16] = a2;
    }

    // ---- PV ----
    const hfrag pa1 = *(const hfrag*)&Pl[wave][0][lr][g * 8];
    const hfrag pa2 = *(const hfrag*)&Pl[wave][1][lr][g * 8];
#pragma unroll
    for (int nf = 0; nf < 8; ++nf) {
      const int vs = 8 * ((g + nf) & 3);
      const hfrag vb1 = *(const hfrag*)&Vt[0][nf * 16 + lr][vs];
      const hfrag vb2 = *(const hfrag*)&Vt[1][nf * 16 + lr][vs];
      oM[nf] = __builtin_amdgcn_mfma_f32_16x16x32_f16(pa1, vb1, oM[nf], 0, 0, 0);
      oS[nf] = __builtin_amdgcn_mfma_f32_16x16x32_f16(pa1, vb2, oS[nf], 0, 0, 0);
      oS[nf] = __builtin_amdgcn_mfma_f32_16x16x32_f16(pa2, vb1, oS[nf], 0, 0, 0);
    }
  }

  // ---- epilogue ----
  float* Og = O + base + (size_t)(qt * 64 + wave * 16) * DDIM;
#pragma unroll
  for (int r = 0; r < 4; ++r) {
    const float invl = 1.0f / l[r];
    float* orow = Og + (size_t)(g * 4 + r) * DDIM;
#pragma unroll
    for (int nf = 0; nf < 8; ++nf)
      orow[nf * 16 + lr] = (oM[nf][r] + oS[nf][r] * INV2048) * invl;
  }
}

// ---------------------------------------------------------------------------
// Final: y = lif2(f32) + spikes2(u8); LayerNorm; float32 store.
// ---------------------------------------------------------------------------
__global__ __launch_bounds__(256)
void ln_kernel(const float* __restrict__ a, const uint8_t* __restrict__ s8,
               const float* __restrict__ gamma, const float* __restrict__ beta,
               float* __restrict__ out) {
  const int row = blockIdx.x;
  const int tid = threadIdx.x;
  const size_t base = (size_t)row * DDIM;
  const float4 av = *(const float4*)(a + base + tid * 4);
  const uchar4 sv = *(const uchar4*)(s8 + base + tid * 4);
  const float y0 = av.x + (float)sv.x, y1 = av.y + (float)sv.y;
  const float y2 = av.z + (float)sv.z, y3 = av.w + (float)sv.w;
  float s = (y0 + y1) + (y2 + y3);
  float q = (y0 * y0 + y1 * y1) + (y2 * y2 + y3 * y3);
#pragma unroll
  for (int off = 1; off < 64; off <<= 1) {
    s += __shfl_xor(s, off);
    q += __shfl_xor(q, off);
  }
  __shared__ float red[8];
  const int wid = tid >> 6;
  if ((tid & 63) == 0) { red[wid * 2] = s; red[wid * 2 + 1] = q; }
  __syncthreads();
  const float ts = (red[0] + red[2]) + (red[4] + red[6]);
  const float tq = (red[1] + red[3]) + (red[5] + red[7]);
  const float mu  = ts * (1.0f / 1024.0f);
  const float var = tq * (1.0f / 1024.0f) - mu * mu;
  const float rs  = 1.0f / sqrtf(var + 1e-5f);
  const int d = tid * 4;
  const float4 gv  = *(const float4*)(gamma + d);
  const float4 btv = *(const float4*)(beta + d);
  float4 r;
  r.x = (y0 - mu) * rs * gv.x + btv.x;
  r.y = (y1 - mu) * rs * gv.y + btv.y;
  r.z = (y2 - mu) * rs * gv.z + btv.z;
  r.w = (y3 - mu) * rs * gv.w + btv.w;
  *(float4*)(out + base + d) = r;
}

// ---------------------------------------------------------------------------
// Workspace: 4 f32 slots (A,C,D,E) 67.1 MB + u8 spikes 4.2 MB + B planes
// 12 MB = 83.3 MB (ws_size >= 83.9 MB proven R1/R2).
// ---------------------------------------------------------------------------
extern "C" void kernel_launch(void* const* d_in, const int* in_sizes, int n_in,
                              void* d_out, int out_size, void* d_ws, size_t ws_size,
                              hipStream_t stream) {
  const float* x       = (const float*)d_in[0];
  const float* context = (const float*)d_in[1];
  const float* Wg  = (const float*)d_in[2];
  const float* bg  = (const float*)d_in[3];
  const float* Wc  = (const float*)d_in[4];
  const float* Wq  = (const float*)d_in[5];
  const float* Wk  = (const float*)d_in[6];
  const float* Wv  = (const float*)d_in[7];
  const float* Wo  = (const float*)d_in[8];
  const float* Wm  = (const float*)d_in[9];
  const float* rWk = (const float*)d_in[10];
  const float* rWv = (const float*)d_in[11];
  const float* rWr = (const float*)d_in[12];
  const float* rWo = (const float*)d_in[13];
  const float* wd  = (const float*)d_in[14];
  const float* uf  = (const float*)d_in[15];
  const float* gamma = (const float*)d_in[16];
  const float* beta  = (const float*)d_in[17];
  float* out = (float*)d_out;   // reference output dtype = float32

  float* w  = (float*)d_ws;
  float*   bA = w;
  float*   bC = w + 1 * NELEM;
  float*   bD = w + 2 * NELEM;
  float*   bE = w + 3 * NELEM;
  uint8_t* bS = (uint8_t*)(w + 4 * NELEM);                          // u8 spikes
  ushort*  pB = (ushort*)((uint8_t*)d_ws + 4 * NELEM * 4 + NELEM);  // B planes

  const dim3 ew(4096);
  constexpr int M1 = 1024 * 1024;   // ushorts per 1024-K plane

  // Stage 1: thalamic gate — K=2048 GEMM over [x | context], gate FUSED
  cvt_h2t<<<dim3(16, 16, 2), 256, 0, stream>>>(Wg, Wc, nullptr, pB, 0, 1024, 2048);
  gemm_k<0, 0, 2048, 1><<<512, 256, 0, stream>>>(x, nullptr, nullptr, context,
                                                 pB, bA, nullptr, nullptr, x, bg);
  // Stage 2: LIF -> spikes2 (u8)
  lif_u8_kernel<<<64, 64, 0, stream>>>(bA, bS);
  // Stage 3: spike self-attention — Q,K,V one N-merged u8 launch
  cvt_h2t<<<dim3(16, 16, 3), 256, 0, stream>>>(Wq, Wk, Wv, pB, 2 * M1, 0, 1024);
  gemm_k<0, 1, 1024, 0><<<1536, 256, 0, stream>>>(bS, bS, bS, nullptr, pB,
                                                  bA, bC, bD, nullptr, nullptr);
  flash_attn<<<512, 256, 0, stream>>>(bA, bC, bD, bA);
  // Stage 3.5 + 4: Wo (A=attn_out) and Wm (A=context) in ONE launch
  cvt_h2t<<<dim3(16, 16, 2), 256, 0, stream>>>(Wo, Wm, nullptr, pB, 2 * M1, 0, 1024);
  gemm_k<0, 0, 1024, 0><<<1024, 256, 0, stream>>>(bA, context, nullptr, nullptr,
                                                  pB, bC, bE, nullptr,
                                                  nullptr, nullptr);
  mod_kernel<<<ew, 256, 0, stream>>>(bC, bE, bD);          // bD = modulated
  // Stage 5: RWKV — k,v,r one 3-way N-merged launch (shared A = bD)
  cvt_h2t<<<dim3(16, 16, 3), 256, 0, stream>>>(rWk, rWv, rWr, pB, 2 * M1, 0, 1024);
  gemm_k<0, 0, 1024, 0><<<1536, 256, 0, stream>>>(bD, bD, bD, nullptr, pB,
                                                  bA, bC, bE, nullptr, nullptr);
  rwkv_kernel<<<64, 64, 0, stream>>>(bA, bC, wd, uf, bA);  // bA = wkv
  rmul_kernel<<<ew, 256, 0, stream>>>(bE, bA, bA);         // bA = sig(r)*wkv
  cvt_h2t<<<dim3(16, 16, 1), 256, 0, stream>>>(rWo, nullptr, nullptr, pB, 0, 0, 1024);
  gemm_k<0, 0, 1024, 0><<<512, 256, 0, stream>>>(bA, nullptr, nullptr, nullptr,
                                                 pB, bC, nullptr, nullptr,
                                                 nullptr, nullptr);
  // Stage 6: output LIF (in-place) + residual + LayerNorm
  lif_ip_kernel<<<64, 64, 0, stream>>>(bC);
  ln_kernel<<<4096, 256, 0, stream>>>(bC, bS, gamma, beta, out);
}